// Round 15
// baseline (316.375 us; speedup 1.0000x reference)
//
#include <hip/hip_runtime.h>
#include <hip/hip_bf16.h>
#include <math.h>

#define B_  4
#define T_  1024
#define D_  1024
#define H_  16
#define HD_ 64
#define DE_ 64
#define NT_ 8
#define NR_ 64
#define NH_ 4

typedef __attribute__((ext_vector_type(8))) short short8;
typedef __attribute__((ext_vector_type(4))) short short4v;
typedef __attribute__((ext_vector_type(2))) unsigned uint2v;
typedef __attribute__((ext_vector_type(4))) float f4;

// fp32 -> bf16 (RNE)
__device__ __forceinline__ short f2bf(float f) {
    unsigned x = __float_as_uint(f);
    unsigned r = (x + 0x7fffu + ((x >> 16) & 1u)) >> 16;
    return (short)r;
}
__device__ __forceinline__ float bf2f(short s) {
    return __uint_as_float(((unsigned)(unsigned short)s) << 16);
}

// XOR-swizzled LDS addressing for 64-short (128B) logical rows (attn only):
// 16B slot index gets row&7 XORed in -> bank group = f(slot') only,
// conflict-free for fixed-column / varying-row b128 access (T2).
__device__ __forceinline__ int swz64(int row, int slot) {
    return row * 64 + ((slot ^ (row & 7)) << 3);
}

// ---------------------------------------------------------------------------
// Fused prep: castx (blocks 0..2047) | weight transposes (2048..3855) |
// ttype (3856..3887) | pnorm (3888..3903, 4 rows/block, wave per row).
// ---------------------------------------------------------------------------
struct TJ { const float* src; short* dst; int K, N, rs, ro, base; };
struct TJobs { TJ j[7]; };

__global__ __launch_bounds__(256) void prep_k(
    const float* __restrict__ x, short* __restrict__ xb, TJobs jb,
    const float* __restrict__ Wt, short* __restrict__ BTe,
    const float* __restrict__ patterns, float* __restrict__ pn)
{
    const int bid = blockIdx.x;
    const int tid = threadIdx.x;
    __shared__ float tile[64][65];

    if (bid < 2048) {                                  // castx: 8 elems/thread
        size_t i = ((size_t)bid * 256 + tid) * 8;
        float4 v0 = *(const float4*)&x[i];
        float4 v1 = *(const float4*)&x[i + 4];
        short8 o;
        o[0] = f2bf(v0.x); o[1] = f2bf(v0.y); o[2] = f2bf(v0.z); o[3] = f2bf(v0.w);
        o[4] = f2bf(v1.x); o[5] = f2bf(v1.y); o[6] = f2bf(v1.z); o[7] = f2bf(v1.w);
        *(short8*)&xb[i] = o;
        return;
    }
    if (bid < 3856) {                                  // tcast jobs (bases +2048)
        int ji = 0;
#pragma unroll
        for (int i = 1; i < 7; i++) if (bid >= jb.j[i].base) ji = i;
        const float* src = jb.j[ji].src;
        short* dst = jb.j[ji].dst;
        const int K = jb.j[ji].K, N = jb.j[ji].N;
        const int rs = jb.j[ji].rs, ro = jb.j[ji].ro;
        int rel = bid - jb.j[ji].base;
        int tiles_n = N >> 6;
        int k0 = (rel / tiles_n) * 64, n0 = (rel % tiles_n) * 64;
        const int r = tid >> 4, c = (tid & 15) * 4;
#pragma unroll
        for (int rep = 0; rep < 4; rep++) {
            int rr = rep * 16 + r;
            float4 v = *(const float4*)&src[(size_t)(k0 + rr) * N + n0 + c];
            tile[rr][c] = v.x; tile[rr][c + 1] = v.y; tile[rr][c + 2] = v.z; tile[rr][c + 3] = v.w;
        }
        __syncthreads();
#pragma unroll
        for (int rep = 0; rep < 4; rep++) {
            int n = rep * 16 + r;
            short4v p;
            p[0] = f2bf(tile[c + 0][n]);
            p[1] = f2bf(tile[c + 1][n]);
            p[2] = f2bf(tile[c + 2][n]);
            p[3] = f2bf(tile[c + 3][n]);
            *(short4v*)&dst[(size_t)((n0 + n) * rs + ro) * K + k0 + c] = p;
        }
        return;
    }
    if (bid < 3888) {                                  // ttype: W_type -> BTe rows 64..71
        int idx = (bid - 3856) * 256 + tid;            // 8192
        int n = idx >> 10, k = idx & 1023;
        BTe[(size_t)(64 + n) * 1024 + k] = f2bf(Wt[k * 8 + n]);
        return;
    }
    // pnorm: 16 blocks x 4 rows, one wave per row
    {
        int r = (bid - 3888) * 4 + (tid >> 6);
        int lane = tid & 63;
        float v = patterns[r * 64 + lane];
        float ss = v * v;
        for (int off = 1; off < 64; off <<= 1) ss += __shfl_xor(ss, off);
        pn[r * 64 + lane] = v / fmaxf(sqrtf(ss), 1e-12f);
    }
}

// ---------------------------------------------------------------------------
// bf16 MFMA GEMM v8 (R10-proven, byte-for-byte): gemm4 schedule, BN=64 tiles,
// sched_barrier(0) pin after prefetch.  AM=4 -> 128x64 tiles (1024 blocks,
// 4/CU); AM=2 -> 64x64 tiles (2048 blocks on the big shapes, ~7-8/CU --
// extends the R6-proven occupancy lever).
// epi: 0 C f32; 1 +resid -> C f32 + Cb1 bf16; 2 split bf16 at col 1024;
// 3 FUSED gate dot -> atomicAdd gsum[row]; 5 interleaved combine.
// ---------------------------------------------------------------------------
template<int AM>
__global__ __launch_bounds__(256) void gemm8(
    const short* __restrict__ A1, const short* __restrict__ A2, int Ks,
    const short* __restrict__ BT,
    float* __restrict__ C, short* __restrict__ Cb1, short* __restrict__ Cb2,
    int M, int N, int K, int epi,
    const float* __restrict__ resid, const float* __restrict__ ent,
    const float* __restrict__ w1e, const float* __restrict__ bias,
    const float* __restrict__ altw, const float* __restrict__ hitsig)
{
    constexpr int BM = AM * 32;
    constexpr int AR = (AM == 4) ? 2 : 4;      // threads per A row
    constexpr int ANV = 64 / AR / 8;           // short8 per thread for A
    __shared__ short As[BM * 72];
    __shared__ short Bs[64 * 72];
    const int tid = threadIdx.x, wave = tid >> 6, lane = tid & 63;
    const int lrow = lane & 15, lq = lane >> 4;
    // XCD swizzle: consecutive bids -> distinct XCDs, M-slab per XCD
    int bid = blockIdx.x;
    int tiles_m = M / BM;
    int mpx = tiles_m >> 3;
    int xcd = bid & 7, idx = bid >> 3;
    int mt = xcd * mpx + (idx % mpx);
    int nt = idx / mpx;
    const int m0 = mt * BM, n0 = nt * 64;
    const int wm = (wave >> 1) * (AM * 16), wn = (wave & 1) * 32;
    const int K2 = K - Ks;
    const int arow = tid / AR, ash = (tid % AR) * (64 / AR);
    const int brow = tid >> 2, bsh = (tid & 3) * 16;

    short8 va[ANV], vb[2];
    auto loadA = [&](int k0) {
        int ka = k0 + ash;
        const short* ap = (ka < Ks)
            ? A1 + (size_t)(m0 + arow) * Ks + ka
            : A2 + (size_t)(m0 + arow) * K2 + (ka - Ks);
#pragma unroll
        for (int u = 0; u < ANV; u++) va[u] = *(const short8*)(ap + u * 8);
    };
    auto loadB = [&](int k0) {
        const short* bp = BT + (size_t)(n0 + brow) * K + k0 + bsh;
#pragma unroll
        for (int u = 0; u < 2; u++) vb[u] = *(const short8*)(bp + u * 8);
    };

    loadA(0); loadB(0);
    f4 acc[AM][2] = {};

    for (int k0 = 0; k0 < K; k0 += 64) {
        __syncthreads();                 // prev-iter LDS readers done
#pragma unroll
        for (int u = 0; u < ANV; u++)
            *(short8*)&As[arow * 72 + ash + u * 8] = va[u];
#pragma unroll
        for (int u = 0; u < 2; u++)
            *(short8*)&Bs[brow * 72 + bsh + u * 8] = vb[u];
        __syncthreads();
        if (k0 + 64 < K) { loadA(k0 + 64); loadB(k0 + 64); }  // in flight over MFMAs
        __builtin_amdgcn_sched_barrier(0);  // pin: loads issue BEFORE MFMA phase
#pragma unroll
        for (int kh = 0; kh < 2; kh++) {
            short8 af[AM], bfv[2];
#pragma unroll
            for (int i = 0; i < AM; i++)
                af[i] = *(short8*)&As[(wm + i * 16 + lrow) * 72 + kh * 32 + lq * 8];
#pragma unroll
            for (int j = 0; j < 2; j++)
                bfv[j] = *(short8*)&Bs[(wn + j * 16 + lrow) * 72 + kh * 32 + lq * 8];
#pragma unroll
            for (int i = 0; i < AM; i++)
#pragma unroll
                for (int j = 0; j < 2; j++)
                    acc[i][j] = __builtin_amdgcn_mfma_f32_16x16x32_bf16(
                        af[i], bfv[j], acc[i][j], 0, 0, 0);
        }
    }

    if (epi == 3) {
#pragma unroll
        for (int i = 0; i < AM; i++) {
#pragma unroll
            for (int r = 0; r < 4; r++) {
                int row = m0 + wm + i * 16 + lq * 4 + r;
                float gp = 0.f;
#pragma unroll
                for (int j = 0; j < 2; j++) {
                    int col = n0 + wn + j * 16 + lrow;
                    float v = acc[i][j][r] + ent[row] * w1e[col] + bias[col];
                    float sv = v * __builtin_amdgcn_rcpf(1.f + __expf(-v));  // silu
                    gp += sv * altw[col];                                    // altw = Wg2
                }
                gp += __shfl_xor(gp, 1);
                gp += __shfl_xor(gp, 2);
                gp += __shfl_xor(gp, 4);
                gp += __shfl_xor(gp, 8);
                if (lrow == 0) atomicAdd(&C[row], gp);
            }
        }
        return;
    }

#pragma unroll
    for (int i = 0; i < AM; i++) {
#pragma unroll
        for (int r = 0; r < 4; r++) {
            int row = m0 + wm + i * 16 + lq * 4 + r;
            float w0 = 0.f, w1 = 0.f, hs = 0.f;
            if (epi == 5) { w0 = altw[row * 2]; w1 = altw[row * 2 + 1]; hs = hitsig[row]; }
#pragma unroll
            for (int j = 0; j < 2; j++) {
                int col = n0 + wn + j * 16 + lrow;
                float v = acc[i][j][r];
                if (epi == 0) {
                    C[(size_t)row * N + col] = v;
                } else if (epi == 1) {
                    v += resid[(size_t)row * N + col];
                    C[(size_t)row * N + col] = v;
                    Cb1[(size_t)row * N + col] = f2bf(v);
                } else if (epi == 2) {
                    if (col < 1024) Cb1[(size_t)row * 1024 + col] = f2bf(v);
                    else            Cb2[(size_t)row * 1024 + col - 1024] = f2bf(v);
                } else {   // 5: interleaved combine (alt pair in adjacent lanes)
                    float other = __shfl_xor(v, 1);
                    if ((lane & 1) == 0) {
                        float cv = (w0 * v + w1 * other) * hs;
                        Cb1[(size_t)row * 1024 + (col >> 1)] = f2bf(cv);
                    }
                }
            }
        }
    }
}

// ---------------------------------------------------------------------------
// Fused vtrans (blocks 0..1023) + ax (1024..1279).
// ---------------------------------------------------------------------------
__global__ __launch_bounds__(256) void vx_k(
    const short* __restrict__ vb, short* __restrict__ vtg,
    const short* __restrict__ nodes_bf, const float* __restrict__ arity_w,
    float* __restrict__ ax)
{
    const int bid = blockIdx.x;
    const int tid = threadIdx.x;
    __shared__ short tile[64 * 72];

    if (bid < 1024) {
        const int b = bid >> 8, h = (bid >> 4) & 15, t0 = (bid & 15) * 64;
        const int row = tid >> 2, c = (tid & 3) * 16;
        const short* p = vb + (size_t)(b * T_ + t0 + row) * D_ + h * 64 + c;
        *(short8*)&tile[row * 72 + c + 0] = *(const short8*)(p + 0);
        *(short8*)&tile[row * 72 + c + 8] = *(const short8*)(p + 8);
        __syncthreads();
        short8 o0, o1;
#pragma unroll
        for (int i = 0; i < 8; i++) o0[i] = tile[(c + i) * 72 + row];
#pragma unroll
        for (int i = 0; i < 8; i++) o1[i] = tile[(c + 8 + i) * 72 + row];
        short* q = vtg + (size_t)((b * H_ + h) * 64 + row) * T_ + t0 + c;
        *(short8*)(q + 0) = o0;
        *(short8*)(q + 8) = o1;
        return;
    }
    {
        int idx = (bid - 1024) * 256 + tid;
        int t = idx & (T_ - 1);
        int h = (idx >> 10) & (H_ - 1);
        int b = idx >> 14;
        const short* np_ = nodes_bf + (((size_t)b * T_ + t) * H_ + h) * HD_;
        float s = 0.f;
#pragma unroll
        for (int d = 0; d < HD_; d += 8) {
            short8 n8 = *(const short8*)&np_[d];
#pragma unroll
            for (int q = 0; q < 8; q++) s += bf2f(n8[q]) * arity_w[h * HD_ + d + q];
        }
        ax[idx] = s;
    }
}

// ---------------------------------------------------------------------------
// MFMA flash attention v9 (R9-proven, byte-for-byte).
// ---------------------------------------------------------------------------
__global__ __launch_bounds__(256) void attn9_k(
    const short* __restrict__ nodes_bf, const short* __restrict__ vtg,
    const float* __restrict__ ax, short* __restrict__ attnp)
{
    const int b = blockIdx.z, h = blockIdx.y, t0 = blockIdx.x * 64;
    const int tid = threadIdx.x;
    const int wave = tid >> 6, lane = tid & 63;
    const int lrow = lane & 15, lq = lane >> 4;
    const int wm = wave * 16;
    const int row = tid >> 2, c4 = tid & 3;

    __shared__ short Ns[2][64 * 64];
    __shared__ short Vt[2][64 * 64];
    __shared__ short Pm[64 * 64];

    // Q fragment: one strided global load, no LDS round-trip
    const short* qp = nodes_bf + (size_t)(b * T_ + t0 + wm + lrow) * D_ + h * 64;
    const short8 bt0 = *(const short8*)(qp + lq * 8);
    const short8 bt1 = *(const short8*)(qp + 32 + lq * 8);
    const float at8 = ax[(size_t)(b * H_ + h) * T_ + t0 + wm + lrow] * 0.125f;

    const short* np0 = nodes_bf + (size_t)(b * T_ + row) * D_ + h * 64 + c4 * 16;
    const short* vp0 = vtg + (size_t)((b * H_ + h) * 64 + row) * T_ + c4 * 16;
    const float* axp_ = ax + (size_t)(b * H_ + h) * T_;

    short8 vn0, vn1, vv0, vv1;
    f4 axv[4];
    auto preload = [&](int s0) {
        const short* np = np0 + (size_t)s0 * D_;
        const short* vp = vp0 + s0;
        vn0 = *(const short8*)(np + 0);
        vn1 = *(const short8*)(np + 8);
        vv0 = *(const short8*)(vp + 0);
        vv1 = *(const short8*)(vp + 8);
#pragma unroll
        for (int j = 0; j < 4; j++)
            axv[j] = *(const f4*)&axp_[s0 + j * 16 + lq * 4];
    };

    preload(0);

    float l_reg = 0.f;
    f4 O[4] = {};
    f4 axc[4];

    for (int t = 0; t < T_ / 64; t++) {
        const int cur = t & 1;
        // stage regs (loaded last iter) into buf[cur]; prev readers of this
        // buffer finished before barrier(t-1).
        *(short8*)&Ns[cur][swz64(row, 2 * c4 + 0)] = vn0;
        *(short8*)&Ns[cur][swz64(row, 2 * c4 + 1)] = vn1;
        *(short8*)&Vt[cur][swz64(row, 2 * c4 + 0)] = vv0;
        *(short8*)&Vt[cur][swz64(row, 2 * c4 + 1)] = vv1;
#pragma unroll
        for (int j = 0; j < 4; j++) axc[j] = axv[j];    // current tile's ax
        __syncthreads();                       // stage visible; ONE barrier/tile
        if (t + 1 < T_ / 64) preload((t + 1) * 64);  // in flight over compute
        __builtin_amdgcn_sched_barrier(0);     // pin loads before compute

        float psum = 0.f;
#pragma unroll
        for (int j = 0; j < 4; j++) {
            short8 a0 = *(short8*)&Ns[cur][swz64(j * 16 + lrow, lq)];
            short8 a1 = *(short8*)&Ns[cur][swz64(j * 16 + lrow, 4 + lq)];
            f4 s = {0.f, 0.f, 0.f, 0.f};
            __builtin_amdgcn_s_setprio(1);
            s = __builtin_amdgcn_mfma_f32_16x16x32_bf16(a0, bt0, s, 0, 0, 0);
            s = __builtin_amdgcn_mfma_f32_16x16x32_bf16(a1, bt1, s, 0, 0, 0);
            __builtin_amdgcn_s_setprio(0);
            // mK = K*sigmoid_poly(z), K = 0.125*log2(e); p = exp2(score * mK)
            float p0, p1, p2, p3;
            {
                float z, zz, t1, mK;
                z = fmaf(axc[j][0], 0.125f, at8); zz = z * z;
                t1 = fmaf(zz, -0.0037570183f, 0.04508422f);
                mK = fmaf(z, t1, 0.09016844f);
                p0 = __builtin_amdgcn_exp2f(s[0] * mK);
                z = fmaf(axc[j][1], 0.125f, at8); zz = z * z;
                t1 = fmaf(zz, -0.0037570183f, 0.04508422f);
                mK = fmaf(z, t1, 0.09016844f);
                p1 = __builtin_amdgcn_exp2f(s[1] * mK);
                z = fmaf(axc[j][2], 0.125f, at8); zz = z * z;
                t1 = fmaf(zz, -0.0037570183f, 0.04508422f);
                mK = fmaf(z, t1, 0.09016844f);
                p2 = __builtin_amdgcn_exp2f(s[2] * mK);
                z = fmaf(axc[j][3], 0.125f, at8); zz = z * z;
                t1 = fmaf(zz, -0.0037570183f, 0.04508422f);
                mK = fmaf(z, t1, 0.09016844f);
                p3 = __builtin_amdgcn_exp2f(s[3] * mK);
            }
            psum += (p0 + p1) + (p2 + p3);
            unsigned u0, u1;
            asm("v_cvt_pk_bf16_f32 %0, %1, %2" : "=v"(u0) : "v"(p0), "v"(p1));
            asm("v_cvt_pk_bf16_f32 %0, %1, %2" : "=v"(u1) : "v"(p2), "v"(p3));
            uint2v uu; uu[0] = u0; uu[1] = u1;
            *(uint2v*)&Pm[swz64(wm + lrow, 2 * j + (lq >> 1)) + (lq & 1) * 4] = uu;
        }
        l_reg += psum;
        // Pm rows are wave-private: no block barrier needed before PV.

        short8 pa0 = *(short8*)&Pm[swz64(wm + lrow, lq)];
        short8 pa1 = *(short8*)&Pm[swz64(wm + lrow, 4 + lq)];
        __builtin_amdgcn_s_setprio(1);
#pragma unroll
        for (int dj = 0; dj < 4; dj++) {
            short8 v0 = *(short8*)&Vt[cur][swz64(dj * 16 + lrow, lq)];
            short8 v1 = *(short8*)&Vt[cur][swz64(dj * 16 + lrow, 4 + lq)];
            O[dj] = __builtin_amdgcn_mfma_f32_16x16x32_bf16(pa0, v0, O[dj], 0, 0, 0);
            O[dj] = __builtin_amdgcn_mfma_f32_16x16x32_bf16(pa1, v1, O[dj], 0, 0, 0);
        }
        __builtin_amdgcn_s_setprio(0);
    }

    // deferred cross-lane row-sum (lanes with equal lrow hold the same t-row)
    l_reg += __shfl_xor(l_reg, 16);
    l_reg += __shfl_xor(l_reg, 32);

    float linv[4];
#pragma unroll
    for (int r = 0; r < 4; r++)
        linv[r] = __builtin_amdgcn_rcpf(__shfl(l_reg, lq * 4 + r));
#pragma unroll
    for (int dj = 0; dj < 4; dj++)
#pragma unroll
        for (int r = 0; r < 4; r++)
            attnp[(size_t)(b * T_ + t0 + wm + lq * 4 + r) * D_ + h * 64 + dj * 16 + lrow] =
                f2bf(O[dj][r] * linv[r]);
}

// ---------------------------------------------------------------------------
// Per-token tail: entropy, event norm, sim (LDS), butterfly top-4, softmaxes.
// Also zeroes gsum[m] ahead of the Wg1 gemm's fused-gate atomics.
// ---------------------------------------------------------------------------
__global__ __launch_bounds__(256) void token2_k(
    const float* __restrict__ evlg, const float* __restrict__ pn,
    const float* __restrict__ patterns, const float* __restrict__ W_alt,
    const float* __restrict__ log_temp,
    float* __restrict__ entn, float* __restrict__ altw, float* __restrict__ hitsig,
    float* __restrict__ gsum)
{
    const int tid = threadIdx.x, wave = tid >> 6, lane = tid & 63;
    __shared__ float pn_sh[64 * 68];
    __shared__ float pat_sh[64 * 68];
    __shared__ float en_sh[4][68];
    {
        int row = tid >> 2, c = (tid & 3) * 16;
#pragma unroll
        for (int u = 0; u < 4; u++) {
            *(float4*)&pn_sh[row * 68 + c + u * 4]  = *(const float4*)&pn[row * 64 + c + u * 4];
            *(float4*)&pat_sh[row * 68 + c + u * 4] = *(const float4*)&patterns[row * 64 + c + u * 4];
        }
    }
    float temp = expf(log_temp[0]);
    temp = fminf(fmaxf(temp, 0.01f), 10.f);
    const float tinv = 1.f / temp;
    __syncthreads();

#pragma unroll
    for (int rep = 0; rep < 2; rep++) {
        const int m = blockIdx.x * 8 + wave * 2 + rep;
        float ev = evlg[(size_t)m * 128 + lane];
        float ss = ev * ev;
        for (int off = 1; off < 64; off <<= 1) ss += __shfl_xor(ss, off);
        float en = ev * __builtin_amdgcn_rcpf(fmaxf(sqrtf(ss), 1e-12f));
        en_sh[wave][lane] = en;
        float entv;
        {
            float lgt = evlg[(size_t)m * 128 + 64 + (lane & 7)];
            float mx = lgt;
            for (int off = 1; off < 8; off <<= 1) mx = fmaxf(mx, __shfl_xor(mx, off));
            float p = __expf(lgt - mx);
            float sum = p;
            for (int off = 1; off < 8; off <<= 1) sum += __shfl_xor(sum, off);
            float pi = p / sum;
            float term = -pi * __logf(pi + 1e-10f);
            float e = term;
            for (int off = 1; off < 8; off <<= 1) e += __shfl_xor(e, off);
            entv = e * 0.4808983f;   // 1/ln(8)
        }
        float sim = 0.f;
#pragma unroll
        for (int u = 0; u < 16; u++) {
            float4 e4 = *(float4*)&en_sh[wave][u * 4];
            float4 p4 = *(float4*)&pn_sh[lane * 68 + u * 4];
            sim += e4.x * p4.x + e4.y * p4.y + e4.z * p4.z + e4.w * p4.w;
        }
        float v = sim;
        float tv[NH_]; int tix[NH_];
#pragma unroll
        for (int kk = 0; kk < NH_; kk++) {
            float mv = v; int mi = lane;
            if (v == -1e30f) mi = 127;
            for (int off = 1; off < 64; off <<= 1) {
                float ov = __shfl_xor(mv, off);
                int   oi = __shfl_xor(mi, off);
                if (ov > mv || (ov == mv && oi < mi)) { mv = ov; mi = oi; }
            }
            tv[kk] = mv; tix[kk] = mi;
            if (lane == mi) v = -1e30f;
        }
        float hmx = tv[0];
        float hw[NH_], hsum = 0.f;
#pragma unroll
        for (int kk = 0; kk < NH_; kk++) { hw[kk] = __expf((tv[kk] - hmx) * tinv); hsum += hw[kk]; }
        float hsr = __builtin_amdgcn_rcpf(hsum);
        float wp = 0.f;
#pragma unroll
        for (int kk = 0; kk < NH_; kk++) wp += hw[kk] * hsr * pat_sh[tix[kk] * 68 + lane];
        float a0 = wp * W_alt[lane * 2 + 0];
        float a1 = wp * W_alt[lane * 2 + 1];
        for (int off = 1; off < 64; off <<= 1) {
            a0 += __shfl_xor(a0, off);
            a1 += __shfl_xor(a1, off);
        }
        a0 *= tinv; a1 *= tinv;
        float amx = fmaxf(a0, a1);
        float e0 = __expf(a0 - amx), e1 = __expf(a1 - amx);
        if (lane == 0) {
            float zr = __builtin_amdgcn_rcpf(e0 + e1);
            altw[m * 2 + 0] = e0 * zr;
            altw[m * 2 + 1] = e1 * zr;
            hitsig[m] = __builtin_amdgcn_rcpf(1.f + __expf(-tv[0]));
            entn[m] = entv;
            gsum[m] = 0.f;
        }
    }
}

// ---------------------------------------------------------------------------
// gate final: g = sigmoid(gsum[m] + bg2); out = x1 + g * actions.
// ---------------------------------------------------------------------------
__global__ __launch_bounds__(256) void gate2_k(
    const float* __restrict__ gsum, const float* __restrict__ bg2,
    const float* __restrict__ x1, const short* __restrict__ actions_bf,
    float* __restrict__ out)
{
    const int m = blockIdx.x, tid = threadIdx.x;
    float g = 1.f / (1.f + __expf(-(gsum[m] + bg2[0])));
    size_t i = (size_t)m * D_ + tid * 4;
    float4 xv = *(const float4*)&x1[i];
    short4v av = *(const short4v*)&actions_bf[i];
    float4 o;
    o.x = xv.x + g * bf2f(av[0]);
    o.y = xv.y + g * bf2f(av[1]);
    o.z = xv.z + g * bf2f(av[2]);
    o.w = xv.w + g * bf2f(av[3]);
    *(float4*)&out[i] = o;
}

// ---------------------------------------------------------------------------
extern "C" void kernel_launch(void* const* d_in, const int* in_sizes, int n_in,
                              void* d_out, int out_size, void* d_ws, size_t ws_size,
                              hipStream_t stream)
{
    const float* x        = (const float*)d_in[0];
    const float* W_node   = (const float*)d_in[1];
    const float* W_value  = (const float*)d_in[2];
    const float* W_out    = (const float*)d_in[3];
    const float* arity_w  = (const float*)d_in[4];
    const float* W_event  = (const float*)d_in[5];
    const float* W_type   = (const float*)d_in[6];
    const float* patterns = (const float*)d_in[7];
    const float* W_act    = (const float*)d_in[8];
    const float* W_alt    = (const float*)d_in[9];
    const float* log_temp = (const float*)d_in[10];
    const float* Wg1      = (const float*)d_in[11];
    const float* bg1      = (const float*)d_in[12];
    const float* Wg2      = (const float*)d_in[13];
    const float* bg2      = (const float*)d_in[14];
    float* out = (float*)d_out;

    const int M = B_ * T_;                          // 4096
    // --- fp32 ---
    float* x1     = (float*)d_ws;                   // 4M floats
    float* evlg   = x1 + 4194304;                   // 512K  [M][128]
    float* axp    = evlg + 524288;                  // 64K
    float* pn     = axp + 65536;
    float* entn   = pn + 4096;
    float* altw   = entn + 4096;
    float* hitsig = altw + 8192;
    float* gsum   = axp;                            // aliases axp (dead post-attn)
    // --- bf16 ---
    short* big       = (short*)(hitsig + 4096);
    short* xbf       = big;                         // 4M (x cast; attn out)
    short* nodes_bf  = big + 1 * 4194304;
    short* values_bf = big + 2 * 4194304;
    short* vtg       = big + 3 * 4194304;           // later actions_bf
    short* x1_bf     = big + 4 * 4194304;
    short* wts       = big + 5 * 4194304;
    short* WnvT  = wts;                             // 2M  ([2048][1024])
    short* WoT   = wts + 2 * 1048576;               // 1M
    short* WaT   = wts + 3 * 1048576;               // 2M  interleaved [2048][1024]
    short* Wg1T  = wts + 5 * 1048576;               // 2M  ([1024][2048])
    short* BTe   = wts + 7 * 1048576;               // 128K shorts ([128][1024])
    short* actions_bf = vtg;

    dim3 blk(256);
    dim3 g_bh(T_ / 64, H_, B_);

    TJobs jb;   // bases offset +2048 (castx occupies blocks 0..2047)
    jb.j[0] = {W_node,            WnvT,           1024, 1024, 1, 0, 2048};
    jb.j[1] = {W_value,           WnvT + 1048576, 1024, 1024, 1, 0, 2304};
    jb.j[2] = {W_out,             WoT,            1024, 1024, 1, 0, 2560};
    jb.j[3] = {W_act,             WaT,            1024, 1024, 2, 0, 2816};
    jb.j[4] = {W_act + 1048576,   WaT,            1024, 1024, 2, 1, 3072};
    jb.j[5] = {Wg1,               Wg1T,           2048, 1024, 1, 0, 3328};
    jb.j[6] = {W_event,           BTe,            1024,   64, 1, 0, 3840};
    prep_k<<<3904, blk, 0, stream>>>(x, xbf, jb, W_type, BTe, patterns, pn);

    // QKV fused: 64x64 tiles -> 2048 blocks (~7-8/CU) EXPERIMENT
    gemm8<2><<<2048, blk, 0, stream>>>(xbf, xbf, D_, WnvT,
        nullptr, nodes_bf, values_bf, M, 2048, D_, 2,
        nullptr, nullptr, nullptr, nullptr, nullptr, nullptr);
    vx_k<<<1280, blk, 0, stream>>>(values_bf, vtg, nodes_bf, arity_w, axp);
    attn9_k<<<g_bh, blk, 0, stream>>>(nodes_bf, vtg, axp, xbf);   // xbf = attn out
    // x1 = attn@W_out + x: 64x64 tiles -> 1024 blocks
    gemm8<2><<<1024, blk, 0, stream>>>(xbf, xbf, D_, WoT,
        x1, x1_bf, nullptr, M, D_, D_, 1,
        x, nullptr, nullptr, nullptr, nullptr, nullptr);
    // events + type logits: N=128, 64x64 tiles -> 128 blocks
    gemm8<2><<<128, blk, 0, stream>>>(x1_bf, x1_bf, D_, BTe,
        evlg, nullptr, nullptr, M, 128, D_, 0,
        nullptr, nullptr, nullptr, nullptr, nullptr, nullptr);
    token2_k<<<M / 8, blk, 0, stream>>>(evlg, pn, patterns, W_alt, log_temp,
                                        entn, altw, hitsig, gsum);
    // actions: SAME SHAPE as QKV, stays on gemm8<4> (1024 blocks) as control
    gemm8<4><<<1024, blk, 0, stream>>>(x1_bf, x1_bf, D_, WaT,
        nullptr, actions_bf, nullptr, M, 2048, D_, 5,
        nullptr, nullptr, nullptr, nullptr, altw, hitsig);
    // Wg1 gemm with FUSED gate dot: gsum[row] += silu(...)*Wg2[col]
    gemm8<2><<<1024, blk, 0, stream>>>(x1_bf, actions_bf, D_, Wg1T,
        gsum, nullptr, nullptr, M, D_, 2048, 3,
        nullptr, entn, Wg1 + (size_t)2048 * D_, bg1, Wg2, nullptr);
    gate2_k<<<M, blk, 0, stream>>>(gsum, bg2, x1, actions_bf, out);
}

// Round 16
// 314.475 us; speedup vs baseline: 1.0060x; 1.0060x over previous
//
#include <hip/hip_runtime.h>
#include <hip/hip_bf16.h>
#include <math.h>

#define B_  4
#define T_  1024
#define D_  1024
#define H_  16
#define HD_ 64
#define DE_ 64
#define NT_ 8
#define NR_ 64
#define NH_ 4

typedef __attribute__((ext_vector_type(8))) short short8;
typedef __attribute__((ext_vector_type(4))) short short4v;
typedef __attribute__((ext_vector_type(2))) unsigned uint2v;
typedef __attribute__((ext_vector_type(4))) float f4;

typedef __attribute__((address_space(1))) const unsigned int guint;
typedef __attribute__((address_space(3))) unsigned int suint;

// fp32 -> bf16 (RNE)
__device__ __forceinline__ short f2bf(float f) {
    unsigned x = __float_as_uint(f);
    unsigned r = (x + 0x7fffu + ((x >> 16) & 1u)) >> 16;
    return (short)r;
}
__device__ __forceinline__ float bf2f(short s) {
    return __uint_as_float(((unsigned)(unsigned short)s) << 16);
}

// XOR-swizzled LDS addressing for 64-short (128B) logical rows:
// 16B slot index gets row&7 XORed in -> bank group = f(slot') only,
// conflict-free for fixed-column / varying-row b128 access (T2).
__device__ __forceinline__ int swz64(int row, int slot) {
    return row * 64 + ((slot ^ (row & 7)) << 3);
}

// ---------------------------------------------------------------------------
// Fused prep: castx (blocks 0..2047) | weight transposes (2048..3855) |
// ttype (3856..3887) | pnorm (3888..3903, 4 rows/block, wave per row).
// ---------------------------------------------------------------------------
struct TJ { const float* src; short* dst; int K, N, rs, ro, base; };
struct TJobs { TJ j[7]; };

__global__ __launch_bounds__(256) void prep_k(
    const float* __restrict__ x, short* __restrict__ xb, TJobs jb,
    const float* __restrict__ Wt, short* __restrict__ BTe,
    const float* __restrict__ patterns, float* __restrict__ pn)
{
    const int bid = blockIdx.x;
    const int tid = threadIdx.x;
    __shared__ float tile[64][65];

    if (bid < 2048) {                                  // castx: 8 elems/thread
        size_t i = ((size_t)bid * 256 + tid) * 8;
        float4 v0 = *(const float4*)&x[i];
        float4 v1 = *(const float4*)&x[i + 4];
        short8 o;
        o[0] = f2bf(v0.x); o[1] = f2bf(v0.y); o[2] = f2bf(v0.z); o[3] = f2bf(v0.w);
        o[4] = f2bf(v1.x); o[5] = f2bf(v1.y); o[6] = f2bf(v1.z); o[7] = f2bf(v1.w);
        *(short8*)&xb[i] = o;
        return;
    }
    if (bid < 3856) {                                  // tcast jobs (bases +2048)
        int ji = 0;
#pragma unroll
        for (int i = 1; i < 7; i++) if (bid >= jb.j[i].base) ji = i;
        const float* src = jb.j[ji].src;
        short* dst = jb.j[ji].dst;
        const int K = jb.j[ji].K, N = jb.j[ji].N;
        const int rs = jb.j[ji].rs, ro = jb.j[ji].ro;
        int rel = bid - jb.j[ji].base;
        int tiles_n = N >> 6;
        int k0 = (rel / tiles_n) * 64, n0 = (rel % tiles_n) * 64;
        const int r = tid >> 4, c = (tid & 15) * 4;
#pragma unroll
        for (int rep = 0; rep < 4; rep++) {
            int rr = rep * 16 + r;
            float4 v = *(const float4*)&src[(size_t)(k0 + rr) * N + n0 + c];
            tile[rr][c] = v.x; tile[rr][c + 1] = v.y; tile[rr][c + 2] = v.z; tile[rr][c + 3] = v.w;
        }
        __syncthreads();
#pragma unroll
        for (int rep = 0; rep < 4; rep++) {
            int n = rep * 16 + r;
            short4v p;
            p[0] = f2bf(tile[c + 0][n]);
            p[1] = f2bf(tile[c + 1][n]);
            p[2] = f2bf(tile[c + 2][n]);
            p[3] = f2bf(tile[c + 3][n]);
            *(short4v*)&dst[(size_t)((n0 + n) * rs + ro) * K + k0 + c] = p;
        }
        return;
    }
    if (bid < 3888) {                                  // ttype: W_type -> BTe rows 64..71
        int idx = (bid - 3856) * 256 + tid;            // 8192
        int n = idx >> 10, k = idx & 1023;
        BTe[(size_t)(64 + n) * 1024 + k] = f2bf(Wt[k * 8 + n]);
        return;
    }
    // pnorm: 16 blocks x 4 rows, one wave per row
    {
        int r = (bid - 3888) * 4 + (tid >> 6);
        int lane = tid & 63;
        float v = patterns[r * 64 + lane];
        float ss = v * v;
        for (int off = 1; off < 64; off <<= 1) ss += __shfl_xor(ss, off);
        pn[r * 64 + lane] = v / fmaxf(sqrtf(ss), 1e-12f);
    }
}

// ---------------------------------------------------------------------------
// bf16 MFMA GEMM v8 (R10-proven, byte-for-byte): gemm4 schedule, BN=64 tiles,
// sched_barrier(0) pin after prefetch.
// epi: 0 C f32; 1 +resid -> C f32 + Cb1 bf16; 2 split bf16 at col 1024;
// 3 FUSED gate dot -> atomicAdd gsum[row]; 5 interleaved combine.
// ---------------------------------------------------------------------------
template<int AM>
__global__ __launch_bounds__(256) void gemm8(
    const short* __restrict__ A1, const short* __restrict__ A2, int Ks,
    const short* __restrict__ BT,
    float* __restrict__ C, short* __restrict__ Cb1, short* __restrict__ Cb2,
    int M, int N, int K, int epi,
    const float* __restrict__ resid, const float* __restrict__ ent,
    const float* __restrict__ w1e, const float* __restrict__ bias,
    const float* __restrict__ altw, const float* __restrict__ hitsig)
{
    constexpr int BM = AM * 32;
    constexpr int AR = (AM == 4) ? 2 : 4;      // threads per A row
    constexpr int ANV = 64 / AR / 8;           // short8 per thread for A
    __shared__ short As[BM * 72];
    __shared__ short Bs[64 * 72];
    const int tid = threadIdx.x, wave = tid >> 6, lane = tid & 63;
    const int lrow = lane & 15, lq = lane >> 4;
    // XCD swizzle: consecutive bids -> distinct XCDs, M-slab per XCD
    int bid = blockIdx.x;
    int tiles_m = M / BM;
    int mpx = tiles_m >> 3;
    int xcd = bid & 7, idx = bid >> 3;
    int mt = xcd * mpx + (idx % mpx);
    int nt = idx / mpx;
    const int m0 = mt * BM, n0 = nt * 64;
    const int wm = (wave >> 1) * (AM * 16), wn = (wave & 1) * 32;
    const int K2 = K - Ks;
    const int arow = tid / AR, ash = (tid % AR) * (64 / AR);
    const int brow = tid >> 2, bsh = (tid & 3) * 16;

    short8 va[ANV], vb[2];
    auto loadA = [&](int k0) {
        int ka = k0 + ash;
        const short* ap = (ka < Ks)
            ? A1 + (size_t)(m0 + arow) * Ks + ka
            : A2 + (size_t)(m0 + arow) * K2 + (ka - Ks);
#pragma unroll
        for (int u = 0; u < ANV; u++) va[u] = *(const short8*)(ap + u * 8);
    };
    auto loadB = [&](int k0) {
        const short* bp = BT + (size_t)(n0 + brow) * K + k0 + bsh;
#pragma unroll
        for (int u = 0; u < 2; u++) vb[u] = *(const short8*)(bp + u * 8);
    };

    loadA(0); loadB(0);
    f4 acc[AM][2] = {};

    for (int k0 = 0; k0 < K; k0 += 64) {
        __syncthreads();                 // prev-iter LDS readers done
#pragma unroll
        for (int u = 0; u < ANV; u++)
            *(short8*)&As[arow * 72 + ash + u * 8] = va[u];
#pragma unroll
        for (int u = 0; u < 2; u++)
            *(short8*)&Bs[brow * 72 + bsh + u * 8] = vb[u];
        __syncthreads();
        if (k0 + 64 < K) { loadA(k0 + 64); loadB(k0 + 64); }  // in flight over MFMAs
        __builtin_amdgcn_sched_barrier(0);  // pin: loads issue BEFORE MFMA phase
#pragma unroll
        for (int kh = 0; kh < 2; kh++) {
            short8 af[AM], bfv[2];
#pragma unroll
            for (int i = 0; i < AM; i++)
                af[i] = *(short8*)&As[(wm + i * 16 + lrow) * 72 + kh * 32 + lq * 8];
#pragma unroll
            for (int j = 0; j < 2; j++)
                bfv[j] = *(short8*)&Bs[(wn + j * 16 + lrow) * 72 + kh * 32 + lq * 8];
#pragma unroll
            for (int i = 0; i < AM; i++)
#pragma unroll
                for (int j = 0; j < 2; j++)
                    acc[i][j] = __builtin_amdgcn_mfma_f32_16x16x32_bf16(
                        af[i], bfv[j], acc[i][j], 0, 0, 0);
        }
    }

    if (epi == 3) {
#pragma unroll
        for (int i = 0; i < AM; i++) {
#pragma unroll
            for (int r = 0; r < 4; r++) {
                int row = m0 + wm + i * 16 + lq * 4 + r;
                float gp = 0.f;
#pragma unroll
                for (int j = 0; j < 2; j++) {
                    int col = n0 + wn + j * 16 + lrow;
                    float v = acc[i][j][r] + ent[row] * w1e[col] + bias[col];
                    float sv = v * __builtin_amdgcn_rcpf(1.f + __expf(-v));  // silu
                    gp += sv * altw[col];                                    // altw = Wg2
                }
                gp += __shfl_xor(gp, 1);
                gp += __shfl_xor(gp, 2);
                gp += __shfl_xor(gp, 4);
                gp += __shfl_xor(gp, 8);
                if (lrow == 0) atomicAdd(&C[row], gp);
            }
        }
        return;
    }

#pragma unroll
    for (int i = 0; i < AM; i++) {
#pragma unroll
        for (int r = 0; r < 4; r++) {
            int row = m0 + wm + i * 16 + lq * 4 + r;
            float w0 = 0.f, w1 = 0.f, hs = 0.f;
            if (epi == 5) { w0 = altw[row * 2]; w1 = altw[row * 2 + 1]; hs = hitsig[row]; }
#pragma unroll
            for (int j = 0; j < 2; j++) {
                int col = n0 + wn + j * 16 + lrow;
                float v = acc[i][j][r];
                if (epi == 0) {
                    C[(size_t)row * N + col] = v;
                } else if (epi == 1) {
                    v += resid[(size_t)row * N + col];
                    C[(size_t)row * N + col] = v;
                    Cb1[(size_t)row * N + col] = f2bf(v);
                } else if (epi == 2) {
                    if (col < 1024) Cb1[(size_t)row * 1024 + col] = f2bf(v);
                    else            Cb2[(size_t)row * 1024 + col - 1024] = f2bf(v);
                } else {   // 5: interleaved combine (alt pair in adjacent lanes)
                    float other = __shfl_xor(v, 1);
                    if ((lane & 1) == 0) {
                        float cv = (w0 * v + w1 * other) * hs;
                        Cb1[(size_t)row * 1024 + (col >> 1)] = f2bf(cv);
                    }
                }
            }
        }
    }
}

// ---------------------------------------------------------------------------
// bf16 MFMA GEMM v11: global_load_lds + double-buffered LDS + ONE barrier
// per K-step.  Per step: issue gload_lds(t+1 -> buf^1) [no dest VGPRs, no
// ds_write phase] -> ds_read+MFMA buf -> barrier (per-wave vmcnt drain lands
// t+1's writes; all readers of buf done) -> flip.  Loads get a full MFMA
// phase in flight; barrier count HALVED vs gemm8/10.  Only possible with
// gload_lds: reg-staging would force issue right before the barrier (R2).
// BM=64/BN=64, LDS 32 KiB -> 5 blocks/CU.  Staging geometry = gemm10's
// (R14-verified): linear dest, source col pre-XORed, swz64 reads.
// ---------------------------------------------------------------------------
template<int AM>
__global__ __launch_bounds__(256) void gemm11(
    const short* __restrict__ A1, const short* __restrict__ A2, int Ks,
    const short* __restrict__ BT,
    float* __restrict__ C, short* __restrict__ Cb1, short* __restrict__ Cb2,
    int M, int N, int K, int epi,
    const float* __restrict__ resid, const float* __restrict__ ent,
    const float* __restrict__ w1e, const float* __restrict__ bias,
    const float* __restrict__ altw, const float* __restrict__ hitsig)
{
    constexpr int BM = AM * 32;
    constexpr int AISS = BM / 32;              // A gload issues per wave
    __shared__ short As[2][BM * 64];
    __shared__ short Bs[2][64 * 64];
    const int tid = threadIdx.x, wave = tid >> 6, lane = tid & 63;
    const int lrow = lane & 15, lq = lane >> 4;
    int bid = blockIdx.x;
    int tiles_m = M / BM;
    int mpx = tiles_m >> 3;
    int xcd = bid & 7, idx = bid >> 3;
    int mt = xcd * mpx + (idx % mpx);
    int nt = idx / mpx;
    const int m0 = mt * BM, n0 = nt * 64;
    const int wm = (wave >> 1) * (AM * 16), wn = (wave & 1) * 32;
    const int K2 = K - Ks;

    // staging lane geometry (gemm10-verified): row sub-index l8 (row&7==l8),
    // physical slot lane&7; source col slot pre-XORed -> swz64 reads.
    const int l8 = lane >> 3;
    const int cs = ((lane & 7) ^ l8) << 3;

    auto stageA = [&](int k0, int bu) {
#pragma unroll
        for (int u = 0; u < AISS; u++) {
            int r = wave * (AISS * 8) + u * 8 + l8;
            int ka = k0 + cs;
            const short* gp = (ka < Ks)
                ? A1 + (size_t)(m0 + r) * Ks + ka
                : A2 + (size_t)(m0 + r) * K2 + (ka - Ks);
            short* lp = &As[bu][wave * (AISS * 512) + u * 512];
            __builtin_amdgcn_global_load_lds((guint*)gp, (suint*)lp, 16, 0, 0);
        }
    };
    auto stageB = [&](int k0, int bu) {
#pragma unroll
        for (int u = 0; u < 2; u++) {
            int r = wave * 16 + u * 8 + l8;
            const short* gp = BT + (size_t)(n0 + r) * K + k0 + cs;
            short* lp = &Bs[bu][wave * 1024 + u * 512];
            __builtin_amdgcn_global_load_lds((guint*)gp, (suint*)lp, 16, 0, 0);
        }
    };

    stageA(0, 0); stageB(0, 0);
    __syncthreads();                     // buf0 resident
    f4 acc[AM][2] = {};
    const int nsteps = K >> 6;
    int cur = 0;

    for (int t = 0; t < nsteps; t++) {
        if (t + 1 < nsteps) {            // issue next tile; flies over MFMAs
            stageA((t + 1) << 6, cur ^ 1);
            stageB((t + 1) << 6, cur ^ 1);
        }
        __builtin_amdgcn_sched_barrier(0);  // keep issue order structural
#pragma unroll
        for (int kh = 0; kh < 2; kh++) {
            short8 af[AM], bfv[2];
#pragma unroll
            for (int i = 0; i < AM; i++)
                af[i] = *(short8*)&As[cur][swz64(wm + i * 16 + lrow, kh * 4 + lq)];
#pragma unroll
            for (int j = 0; j < 2; j++)
                bfv[j] = *(short8*)&Bs[cur][swz64(wn + j * 16 + lrow, kh * 4 + lq)];
#pragma unroll
            for (int i = 0; i < AM; i++)
#pragma unroll
                for (int j = 0; j < 2; j++)
                    acc[i][j] = __builtin_amdgcn_mfma_f32_16x16x32_bf16(
                        af[i], bfv[j], acc[i][j], 0, 0, 0);
        }
        __syncthreads();                 // drain loads (t+1 resident); readers done
        cur ^= 1;
    }

    if (epi == 3) {
#pragma unroll
        for (int i = 0; i < AM; i++) {
#pragma unroll
            for (int r = 0; r < 4; r++) {
                int row = m0 + wm + i * 16 + lq * 4 + r;
                float gp = 0.f;
#pragma unroll
                for (int j = 0; j < 2; j++) {
                    int col = n0 + wn + j * 16 + lrow;
                    float v = acc[i][j][r] + ent[row] * w1e[col] + bias[col];
                    float sv = v * __builtin_amdgcn_rcpf(1.f + __expf(-v));  // silu
                    gp += sv * altw[col];
                }
                gp += __shfl_xor(gp, 1);
                gp += __shfl_xor(gp, 2);
                gp += __shfl_xor(gp, 4);
                gp += __shfl_xor(gp, 8);
                if (lrow == 0) atomicAdd(&C[row], gp);
            }
        }
        return;
    }

#pragma unroll
    for (int i = 0; i < AM; i++) {
#pragma unroll
        for (int r = 0; r < 4; r++) {
            int row = m0 + wm + i * 16 + lq * 4 + r;
            float w0 = 0.f, w1 = 0.f, hs = 0.f;
            if (epi == 5) { w0 = altw[row * 2]; w1 = altw[row * 2 + 1]; hs = hitsig[row]; }
#pragma unroll
            for (int j = 0; j < 2; j++) {
                int col = n0 + wn + j * 16 + lrow;
                float v = acc[i][j][r];
                if (epi == 0) {
                    C[(size_t)row * N + col] = v;
                } else if (epi == 1) {
                    v += resid[(size_t)row * N + col];
                    C[(size_t)row * N + col] = v;
                    Cb1[(size_t)row * N + col] = f2bf(v);
                } else if (epi == 2) {
                    if (col < 1024) Cb1[(size_t)row * 1024 + col] = f2bf(v);
                    else            Cb2[(size_t)row * 1024 + col - 1024] = f2bf(v);
                } else {   // 5
                    float other = __shfl_xor(v, 1);
                    if ((lane & 1) == 0) {
                        float cv = (w0 * v + w1 * other) * hs;
                        Cb1[(size_t)row * 1024 + (col >> 1)] = f2bf(cv);
                    }
                }
            }
        }
    }
}

// ---------------------------------------------------------------------------
// Fused vtrans (blocks 0..1023) + ax (1024..1279).
// ---------------------------------------------------------------------------
__global__ __launch_bounds__(256) void vx_k(
    const short* __restrict__ vb, short* __restrict__ vtg,
    const short* __restrict__ nodes_bf, const float* __restrict__ arity_w,
    float* __restrict__ ax)
{
    const int bid = blockIdx.x;
    const int tid = threadIdx.x;
    __shared__ short tile[64 * 72];

    if (bid < 1024) {
        const int b = bid >> 8, h = (bid >> 4) & 15, t0 = (bid & 15) * 64;
        const int row = tid >> 2, c = (tid & 3) * 16;
        const short* p = vb + (size_t)(b * T_ + t0 + row) * D_ + h * 64 + c;
        *(short8*)&tile[row * 72 + c + 0] = *(const short8*)(p + 0);
        *(short8*)&tile[row * 72 + c + 8] = *(const short8*)(p + 8);
        __syncthreads();
        short8 o0, o1;
#pragma unroll
        for (int i = 0; i < 8; i++) o0[i] = tile[(c + i) * 72 + row];
#pragma unroll
        for (int i = 0; i < 8; i++) o1[i] = tile[(c + 8 + i) * 72 + row];
        short* q = vtg + (size_t)((b * H_ + h) * 64 + row) * T_ + t0 + c;
        *(short8*)(q + 0) = o0;
        *(short8*)(q + 8) = o1;
        return;
    }
    {
        int idx = (bid - 1024) * 256 + tid;
        int t = idx & (T_ - 1);
        int h = (idx >> 10) & (H_ - 1);
        int b = idx >> 14;
        const short* np_ = nodes_bf + (((size_t)b * T_ + t) * H_ + h) * HD_;
        float s = 0.f;
#pragma unroll
        for (int d = 0; d < HD_; d += 8) {
            short8 n8 = *(const short8*)&np_[d];
#pragma unroll
            for (int q = 0; q < 8; q++) s += bf2f(n8[q]) * arity_w[h * HD_ + d + q];
        }
        ax[idx] = s;
    }
}

// ---------------------------------------------------------------------------
// MFMA flash attention v9 (R9-proven, byte-for-byte).
// ---------------------------------------------------------------------------
__global__ __launch_bounds__(256) void attn9_k(
    const short* __restrict__ nodes_bf, const short* __restrict__ vtg,
    const float* __restrict__ ax, short* __restrict__ attnp)
{
    const int b = blockIdx.z, h = blockIdx.y, t0 = blockIdx.x * 64;
    const int tid = threadIdx.x;
    const int wave = tid >> 6, lane = tid & 63;
    const int lrow = lane & 15, lq = lane >> 4;
    const int wm = wave * 16;
    const int row = tid >> 2, c4 = tid & 3;

    __shared__ short Ns[2][64 * 64];
    __shared__ short Vt[2][64 * 64];
    __shared__ short Pm[64 * 64];

    // Q fragment: one strided global load, no LDS round-trip
    const short* qp = nodes_bf + (size_t)(b * T_ + t0 + wm + lrow) * D_ + h * 64;
    const short8 bt0 = *(const short8*)(qp + lq * 8);
    const short8 bt1 = *(const short8*)(qp + 32 + lq * 8);
    const float at8 = ax[(size_t)(b * H_ + h) * T_ + t0 + wm + lrow] * 0.125f;

    const short* np0 = nodes_bf + (size_t)(b * T_ + row) * D_ + h * 64 + c4 * 16;
    const short* vp0 = vtg + (size_t)((b * H_ + h) * 64 + row) * T_ + c4 * 16;
    const float* axp_ = ax + (size_t)(b * H_ + h) * T_;

    short8 vn0, vn1, vv0, vv1;
    f4 axv[4];
    auto preload = [&](int s0) {
        const short* np = np0 + (size_t)s0 * D_;
        const short* vp = vp0 + s0;
        vn0 = *(const short8*)(np + 0);
        vn1 = *(const short8*)(np + 8);
        vv0 = *(const short8*)(vp + 0);
        vv1 = *(const short8*)(vp + 8);
#pragma unroll
        for (int j = 0; j < 4; j++)
            axv[j] = *(const f4*)&axp_[s0 + j * 16 + lq * 4];
    };

    preload(0);

    float l_reg = 0.f;
    f4 O[4] = {};
    f4 axc[4];

    for (int t = 0; t < T_ / 64; t++) {
        const int cur = t & 1;
        // stage regs (loaded last iter) into buf[cur]; prev readers of this
        // buffer finished before barrier(t-1).
        *(short8*)&Ns[cur][swz64(row, 2 * c4 + 0)] = vn0;
        *(short8*)&Ns[cur][swz64(row, 2 * c4 + 1)] = vn1;
        *(short8*)&Vt[cur][swz64(row, 2 * c4 + 0)] = vv0;
        *(short8*)&Vt[cur][swz64(row, 2 * c4 + 1)] = vv1;
#pragma unroll
        for (int j = 0; j < 4; j++) axc[j] = axv[j];    // current tile's ax
        __syncthreads();                       // stage visible; ONE barrier/tile
        if (t + 1 < T_ / 64) preload((t + 1) * 64);  // in flight over compute
        __builtin_amdgcn_sched_barrier(0);     // pin loads before compute

        float psum = 0.f;
#pragma unroll
        for (int j = 0; j < 4; j++) {
            short8 a0 = *(short8*)&Ns[cur][swz64(j * 16 + lrow, lq)];
            short8 a1 = *(short8*)&Ns[cur][swz64(j * 16 + lrow, 4 + lq)];
            f4 s = {0.f, 0.f, 0.f, 0.f};
            __builtin_amdgcn_s_setprio(1);
            s = __builtin_amdgcn_mfma_f32_16x16x32_bf16(a0, bt0, s, 0, 0, 0);
            s = __builtin_amdgcn_mfma_f32_16x16x32_bf16(a1, bt1, s, 0, 0, 0);
            __builtin_amdgcn_s_setprio(0);
            // mK = K*sigmoid_poly(z), K = 0.125*log2(e); p = exp2(score * mK)
            float p0, p1, p2, p3;
            {
                float z, zz, t1, mK;
                z = fmaf(axc[j][0], 0.125f, at8); zz = z * z;
                t1 = fmaf(zz, -0.0037570183f, 0.04508422f);
                mK = fmaf(z, t1, 0.09016844f);
                p0 = __builtin_amdgcn_exp2f(s[0] * mK);
                z = fmaf(axc[j][1], 0.125f, at8); zz = z * z;
                t1 = fmaf(zz, -0.0037570183f, 0.04508422f);
                mK = fmaf(z, t1, 0.09016844f);
                p1 = __builtin_amdgcn_exp2f(s[1] * mK);
                z = fmaf(axc[j][2], 0.125f, at8); zz = z * z;
                t1 = fmaf(zz, -0.0037570183f, 0.04508422f);
                mK = fmaf(z, t1, 0.09016844f);
                p2 = __builtin_amdgcn_exp2f(s[2] * mK);
                z = fmaf(axc[j][3], 0.125f, at8); zz = z * z;
                t1 = fmaf(zz, -0.0037570183f, 0.04508422f);
                mK = fmaf(z, t1, 0.09016844f);
                p3 = __builtin_amdgcn_exp2f(s[3] * mK);
            }
            psum += (p0 + p1) + (p2 + p3);
            unsigned u0, u1;
            asm("v_cvt_pk_bf16_f32 %0, %1, %2" : "=v"(u0) : "v"(p0), "v"(p1));
            asm("v_cvt_pk_bf16_f32 %0, %1, %2" : "=v"(u1) : "v"(p2), "v"(p3));
            uint2v uu; uu[0] = u0; uu[1] = u1;
            *(uint2v*)&Pm[swz64(wm + lrow, 2 * j + (lq >> 1)) + (lq & 1) * 4] = uu;
        }
        l_reg += psum;
        // Pm rows are wave-private: no block barrier needed before PV.

        short8 pa0 = *(short8*)&Pm[swz64(wm + lrow, lq)];
        short8 pa1 = *(short8*)&Pm[swz64(wm + lrow, 4 + lq)];
        __builtin_amdgcn_s_setprio(1);
#pragma unroll
        for (int dj = 0; dj < 4; dj++) {
            short8 v0 = *(short8*)&Vt[cur][swz64(dj * 16 + lrow, lq)];
            short8 v1 = *(short8*)&Vt[cur][swz64(dj * 16 + lrow, 4 + lq)];
            O[dj] = __builtin_amdgcn_mfma_f32_16x16x32_bf16(pa0, v0, O[dj], 0, 0, 0);
            O[dj] = __builtin_amdgcn_mfma_f32_16x16x32_bf16(pa1, v1, O[dj], 0, 0, 0);
        }
        __builtin_amdgcn_s_setprio(0);
    }

    // deferred cross-lane row-sum (lanes with equal lrow hold the same t-row)
    l_reg += __shfl_xor(l_reg, 16);
    l_reg += __shfl_xor(l_reg, 32);

    float linv[4];
#pragma unroll
    for (int r = 0; r < 4; r++)
        linv[r] = __builtin_amdgcn_rcpf(__shfl(l_reg, lq * 4 + r));
#pragma unroll
    for (int dj = 0; dj < 4; dj++)
#pragma unroll
        for (int r = 0; r < 4; r++)
            attnp[(size_t)(b * T_ + t0 + wm + lq * 4 + r) * D_ + h * 64 + dj * 16 + lrow] =
                f2bf(O[dj][r] * linv[r]);
}

// ---------------------------------------------------------------------------
// Per-token tail: entropy, event norm, sim (LDS), butterfly top-4, softmaxes.
// Also zeroes gsum[m] ahead of the Wg1 gemm's fused-gate atomics.
// ---------------------------------------------------------------------------
__global__ __launch_bounds__(256) void token2_k(
    const float* __restrict__ evlg, const float* __restrict__ pn,
    const float* __restrict__ patterns, const float* __restrict__ W_alt,
    const float* __restrict__ log_temp,
    float* __restrict__ entn, float* __restrict__ altw, float* __restrict__ hitsig,
    float* __restrict__ gsum)
{
    const int tid = threadIdx.x, wave = tid >> 6, lane = tid & 63;
    __shared__ float pn_sh[64 * 68];
    __shared__ float pat_sh[64 * 68];
    __shared__ float en_sh[4][68];
    {
        int row = tid >> 2, c = (tid & 3) * 16;
#pragma unroll
        for (int u = 0; u < 4; u++) {
            *(float4*)&pn_sh[row * 68 + c + u * 4]  = *(const float4*)&pn[row * 64 + c + u * 4];
            *(float4*)&pat_sh[row * 68 + c + u * 4] = *(const float4*)&patterns[row * 64 + c + u * 4];
        }
    }
    float temp = expf(log_temp[0]);
    temp = fminf(fmaxf(temp, 0.01f), 10.f);
    const float tinv = 1.f / temp;
    __syncthreads();

#pragma unroll
    for (int rep = 0; rep < 2; rep++) {
        const int m = blockIdx.x * 8 + wave * 2 + rep;
        float ev = evlg[(size_t)m * 128 + lane];
        float ss = ev * ev;
        for (int off = 1; off < 64; off <<= 1) ss += __shfl_xor(ss, off);
        float en = ev * __builtin_amdgcn_rcpf(fmaxf(sqrtf(ss), 1e-12f));
        en_sh[wave][lane] = en;
        float entv;
        {
            float lgt = evlg[(size_t)m * 128 + 64 + (lane & 7)];
            float mx = lgt;
            for (int off = 1; off < 8; off <<= 1) mx = fmaxf(mx, __shfl_xor(mx, off));
            float p = __expf(lgt - mx);
            float sum = p;
            for (int off = 1; off < 8; off <<= 1) sum += __shfl_xor(sum, off);
            float pi = p / sum;
            float term = -pi * __logf(pi + 1e-10f);
            float e = term;
            for (int off = 1; off < 8; off <<= 1) e += __shfl_xor(e, off);
            entv = e * 0.4808983f;   // 1/ln(8)
        }
        float sim = 0.f;
#pragma unroll
        for (int u = 0; u < 16; u++) {
            float4 e4 = *(float4*)&en_sh[wave][u * 4];
            float4 p4 = *(float4*)&pn_sh[lane * 68 + u * 4];
            sim += e4.x * p4.x + e4.y * p4.y + e4.z * p4.z + e4.w * p4.w;
        }
        float v = sim;
        float tv[NH_]; int tix[NH_];
#pragma unroll
        for (int kk = 0; kk < NH_; kk++) {
            float mv = v; int mi = lane;
            if (v == -1e30f) mi = 127;
            for (int off = 1; off < 64; off <<= 1) {
                float ov = __shfl_xor(mv, off);
                int   oi = __shfl_xor(mi, off);
                if (ov > mv || (ov == mv && oi < mi)) { mv = ov; mi = oi; }
            }
            tv[kk] = mv; tix[kk] = mi;
            if (lane == mi) v = -1e30f;
        }
        float hmx = tv[0];
        float hw[NH_], hsum = 0.f;
#pragma unroll
        for (int kk = 0; kk < NH_; kk++) { hw[kk] = __expf((tv[kk] - hmx) * tinv); hsum += hw[kk]; }
        float hsr = __builtin_amdgcn_rcpf(hsum);
        float wp = 0.f;
#pragma unroll
        for (int kk = 0; kk < NH_; kk++) wp += hw[kk] * hsr * pat_sh[tix[kk] * 68 + lane];
        float a0 = wp * W_alt[lane * 2 + 0];
        float a1 = wp * W_alt[lane * 2 + 1];
        for (int off = 1; off < 64; off <<= 1) {
            a0 += __shfl_xor(a0, off);
            a1 += __shfl_xor(a1, off);
        }
        a0 *= tinv; a1 *= tinv;
        float amx = fmaxf(a0, a1);
        float e0 = __expf(a0 - amx), e1 = __expf(a1 - amx);
        if (lane == 0) {
            float zr = __builtin_amdgcn_rcpf(e0 + e1);
            altw[m * 2 + 0] = e0 * zr;
            altw[m * 2 + 1] = e1 * zr;
            hitsig[m] = __builtin_amdgcn_rcpf(1.f + __expf(-tv[0]));
            entn[m] = entv;
            gsum[m] = 0.f;
        }
    }
}

// ---------------------------------------------------------------------------
// gate final: g = sigmoid(gsum[m] + bg2); out = x1 + g * actions.
// ---------------------------------------------------------------------------
__global__ __launch_bounds__(256) void gate2_k(
    const float* __restrict__ gsum, const float* __restrict__ bg2,
    const float* __restrict__ x1, const short* __restrict__ actions_bf,
    float* __restrict__ out)
{
    const int m = blockIdx.x, tid = threadIdx.x;
    float g = 1.f / (1.f + __expf(-(gsum[m] + bg2[0])));
    size_t i = (size_t)m * D_ + tid * 4;
    float4 xv = *(const float4*)&x1[i];
    short4v av = *(const short4v*)&actions_bf[i];
    float4 o;
    o.x = xv.x + g * bf2f(av[0]);
    o.y = xv.y + g * bf2f(av[1]);
    o.z = xv.z + g * bf2f(av[2]);
    o.w = xv.w + g * bf2f(av[3]);
    *(float4*)&out[i] = o;
}

// ---------------------------------------------------------------------------
extern "C" void kernel_launch(void* const* d_in, const int* in_sizes, int n_in,
                              void* d_out, int out_size, void* d_ws, size_t ws_size,
                              hipStream_t stream)
{
    const float* x        = (const float*)d_in[0];
    const float* W_node   = (const float*)d_in[1];
    const float* W_value  = (const float*)d_in[2];
    const float* W_out    = (const float*)d_in[3];
    const float* arity_w  = (const float*)d_in[4];
    const float* W_event  = (const float*)d_in[5];
    const float* W_type   = (const float*)d_in[6];
    const float* patterns = (const float*)d_in[7];
    const float* W_act    = (const float*)d_in[8];
    const float* W_alt    = (const float*)d_in[9];
    const float* log_temp = (const float*)d_in[10];
    const float* Wg1      = (const float*)d_in[11];
    const float* bg1      = (const float*)d_in[12];
    const float* Wg2      = (const float*)d_in[13];
    const float* bg2      = (const float*)d_in[14];
    float* out = (float*)d_out;

    const int M = B_ * T_;                          // 4096
    // --- fp32 ---
    float* x1     = (float*)d_ws;                   // 4M floats
    float* evlg   = x1 + 4194304;                   // 512K  [M][128]
    float* axp    = evlg + 524288;                  // 64K
    float* pn     = axp + 65536;
    float* entn   = pn + 4096;
    float* altw   = entn + 4096;
    float* hitsig = altw + 8192;
    float* gsum   = axp;                            // aliases axp (dead post-attn)
    // --- bf16 ---
    short* big       = (short*)(hitsig + 4096);
    short* xbf       = big;                         // 4M (x cast; attn out)
    short* nodes_bf  = big + 1 * 4194304;
    short* values_bf = big + 2 * 4194304;
    short* vtg       = big + 3 * 4194304;           // later actions_bf
    short* x1_bf     = big + 4 * 4194304;
    short* wts       = big + 5 * 4194304;
    short* WnvT  = wts;                             // 2M  ([2048][1024])
    short* WoT   = wts + 2 * 1048576;               // 1M
    short* WaT   = wts + 3 * 1048576;               // 2M  interleaved [2048][1024]
    short* Wg1T  = wts + 5 * 1048576;               // 2M  ([1024][2048])
    short* BTe   = wts + 7 * 1048576;               // 128K shorts ([128][1024])
    short* actions_bf = vtg;

    dim3 blk(256);
    dim3 g_bh(T_ / 64, H_, B_);

    TJobs jb;   // bases offset +2048 (castx occupies blocks 0..2047)
    jb.j[0] = {W_node,            WnvT,           1024, 1024, 1, 0, 2048};
    jb.j[1] = {W_value,           WnvT + 1048576, 1024, 1024, 1, 0, 2304};
    jb.j[2] = {W_out,             WoT,            1024, 1024, 1, 0, 2560};
    jb.j[3] = {W_act,             WaT,            1024, 1024, 2, 0, 2816};
    jb.j[4] = {W_act + 1048576,   WaT,            1024, 1024, 2, 1, 3072};
    jb.j[5] = {Wg1,               Wg1T,           2048, 1024, 1, 0, 3328};
    jb.j[6] = {W_event,           BTe,            1024,   64, 1, 0, 3840};
    prep_k<<<3904, blk, 0, stream>>>(x, xbf, jb, W_type, BTe, patterns, pn);

    // QKV fused: gemm11 (gload_lds dbuf, ONE barrier/K-step) EXPERIMENT
    gemm11<2><<<2048, blk, 0, stream>>>(xbf, xbf, D_, WnvT,
        nullptr, nodes_bf, values_bf, M, 2048, D_, 2,
        nullptr, nullptr, nullptr, nullptr, nullptr, nullptr);
    vx_k<<<1280, blk, 0, stream>>>(values_bf, vtg, nodes_bf, arity_w, axp);
    attn9_k<<<g_bh, blk, 0, stream>>>(nodes_bf, vtg, axp, xbf);   // xbf = attn out
    // x1 = attn@W_out + x: 64x64 tiles -> 1024 blocks
    gemm8<2><<<1024, blk, 0, stream>>>(xbf, xbf, D_, WoT,
        x1, x1_bf, nullptr, M, D_, D_, 1,
        x, nullptr, nullptr, nullptr, nullptr, nullptr);
    // events + type logits: N=128, 64x64 tiles -> 128 blocks
    gemm8<2><<<128, blk, 0, stream>>>(x1_bf, x1_bf, D_, BTe,
        evlg, nullptr, nullptr, M, 128, D_, 0,
        nullptr, nullptr, nullptr, nullptr, nullptr, nullptr);
    token2_k<<<M / 8, blk, 0, stream>>>(evlg, pn, patterns, W_alt, log_temp,
                                        entn, altw, hitsig, gsum);
    // actions: SAME SHAPE as QKV, stays on gemm8<4> (1024 blocks) as control
    gemm8<4><<<1024, blk, 0, stream>>>(x1_bf, x1_bf, D_, WaT,
        nullptr, actions_bf, nullptr, M, 2048, D_, 5,
        nullptr, nullptr, nullptr, nullptr, altw, hitsig);
    // Wg1 gemm with FUSED gate dot: gsum[row] += silu(...)*Wg2[col]
    gemm8<2><<<1024, blk, 0, stream>>>(x1_bf, actions_bf, D_, Wg1T,
        gsum, nullptr, nullptr, M, D_, 2048, 3,
        nullptr, entn, Wg1 + (size_t)2048 * D_, bg1, Wg2, nullptr);
    gate2_k<<<M, blk, 0, stream>>>(gsum, bg2, x1, actions_bf, out);
}

// Round 17
// 311.072 us; speedup vs baseline: 1.0170x; 1.0109x over previous
//
#include <hip/hip_runtime.h>
#include <hip/hip_bf16.h>
#include <math.h>

#define B_  4
#define T_  1024
#define D_  1024
#define H_  16
#define HD_ 64
#define DE_ 64
#define NT_ 8
#define NR_ 64
#define NH_ 4

typedef __attribute__((ext_vector_type(8))) short short8;
typedef __attribute__((ext_vector_type(4))) short short4v;
typedef __attribute__((ext_vector_type(2))) unsigned uint2v;
typedef __attribute__((ext_vector_type(4))) float f4;

typedef __attribute__((address_space(1))) const unsigned int guint;
typedef __attribute__((address_space(3))) unsigned int suint;

// fp32 -> bf16 (RNE)
__device__ __forceinline__ short f2bf(float f) {
    unsigned x = __float_as_uint(f);
    unsigned r = (x + 0x7fffu + ((x >> 16) & 1u)) >> 16;
    return (short)r;
}
__device__ __forceinline__ float bf2f(short s) {
    return __uint_as_float(((unsigned)(unsigned short)s) << 16);
}

// XOR-swizzled LDS addressing for 64-short (128B) logical rows:
// 16B slot index gets row&7 XORed in -> bank group = f(slot') only,
// conflict-free for fixed-column / varying-row b128 access (T2).
__device__ __forceinline__ int swz64(int row, int slot) {
    return row * 64 + ((slot ^ (row & 7)) << 3);
}

// ---------------------------------------------------------------------------
// Fused prep: castx (blocks 0..2047) | weight transposes (2048..3855) |
// ttype (3856..3887) | pnorm (3888..3903, 4 rows/block, wave per row).
// ---------------------------------------------------------------------------
struct TJ { const float* src; short* dst; int K, N, rs, ro, base; };
struct TJobs { TJ j[7]; };

__global__ __launch_bounds__(256) void prep_k(
    const float* __restrict__ x, short* __restrict__ xb, TJobs jb,
    const float* __restrict__ Wt, short* __restrict__ BTe,
    const float* __restrict__ patterns, float* __restrict__ pn)
{
    const int bid = blockIdx.x;
    const int tid = threadIdx.x;
    __shared__ float tile[64][65];

    if (bid < 2048) {                                  // castx: 8 elems/thread
        size_t i = ((size_t)bid * 256 + tid) * 8;
        float4 v0 = *(const float4*)&x[i];
        float4 v1 = *(const float4*)&x[i + 4];
        short8 o;
        o[0] = f2bf(v0.x); o[1] = f2bf(v0.y); o[2] = f2bf(v0.z); o[3] = f2bf(v0.w);
        o[4] = f2bf(v1.x); o[5] = f2bf(v1.y); o[6] = f2bf(v1.z); o[7] = f2bf(v1.w);
        *(short8*)&xb[i] = o;
        return;
    }
    if (bid < 3856) {                                  // tcast jobs (bases +2048)
        int ji = 0;
#pragma unroll
        for (int i = 1; i < 7; i++) if (bid >= jb.j[i].base) ji = i;
        const float* src = jb.j[ji].src;
        short* dst = jb.j[ji].dst;
        const int K = jb.j[ji].K, N = jb.j[ji].N;
        const int rs = jb.j[ji].rs, ro = jb.j[ji].ro;
        int rel = bid - jb.j[ji].base;
        int tiles_n = N >> 6;
        int k0 = (rel / tiles_n) * 64, n0 = (rel % tiles_n) * 64;
        const int r = tid >> 4, c = (tid & 15) * 4;
#pragma unroll
        for (int rep = 0; rep < 4; rep++) {
            int rr = rep * 16 + r;
            float4 v = *(const float4*)&src[(size_t)(k0 + rr) * N + n0 + c];
            tile[rr][c] = v.x; tile[rr][c + 1] = v.y; tile[rr][c + 2] = v.z; tile[rr][c + 3] = v.w;
        }
        __syncthreads();
#pragma unroll
        for (int rep = 0; rep < 4; rep++) {
            int n = rep * 16 + r;
            short4v p;
            p[0] = f2bf(tile[c + 0][n]);
            p[1] = f2bf(tile[c + 1][n]);
            p[2] = f2bf(tile[c + 2][n]);
            p[3] = f2bf(tile[c + 3][n]);
            *(short4v*)&dst[(size_t)((n0 + n) * rs + ro) * K + k0 + c] = p;
        }
        return;
    }
    if (bid < 3888) {                                  // ttype: W_type -> BTe rows 64..71
        int idx = (bid - 3856) * 256 + tid;            // 8192
        int n = idx >> 10, k = idx & 1023;
        BTe[(size_t)(64 + n) * 1024 + k] = f2bf(Wt[k * 8 + n]);
        return;
    }
    // pnorm: 16 blocks x 4 rows, one wave per row
    {
        int r = (bid - 3888) * 4 + (tid >> 6);
        int lane = tid & 63;
        float v = patterns[r * 64 + lane];
        float ss = v * v;
        for (int off = 1; off < 64; off <<= 1) ss += __shfl_xor(ss, off);
        pn[r * 64 + lane] = v / fmaxf(sqrtf(ss), 1e-12f);
    }
}

// ---------------------------------------------------------------------------
// bf16 MFMA GEMM v11 (R16-proven on QKV): global_load_lds + double-buffered
// LDS + ONE barrier per K-step.  Per step: issue gload_lds(t+1 -> buf^1)
// [no dest VGPRs, no ds_write phase] -> ds_read+MFMA buf -> barrier (per-wave
// vmcnt drain lands t+1's writes; all readers of buf done) -> flip.  Loads
// get a full MFMA phase in flight; barrier count HALVED vs the 2-barrier
// schedule (the one parameter that measurably moved the GEMM plateau).
// Only possible with gload_lds: reg-staging would force issue right before
// the barrier (R2 pathology).  BM=64, LDS 32 KiB -> 5 blocks/CU.
// Staging geometry R14-verified: linear dest, source col pre-XORed, swz64
// reads.  No staging VGPRs -> immune to R3/R7 recompile-sinking.
// epi: 0 C f32; 1 +resid -> C f32 + Cb1 bf16; 2 split bf16 at col 1024;
// 3 FUSED gate dot -> atomicAdd gsum[row]; 5 interleaved combine.
// ---------------------------------------------------------------------------
template<int AM>
__global__ __launch_bounds__(256) void gemm11(
    const short* __restrict__ A1, const short* __restrict__ A2, int Ks,
    const short* __restrict__ BT,
    float* __restrict__ C, short* __restrict__ Cb1, short* __restrict__ Cb2,
    int M, int N, int K, int epi,
    const float* __restrict__ resid, const float* __restrict__ ent,
    const float* __restrict__ w1e, const float* __restrict__ bias,
    const float* __restrict__ altw, const float* __restrict__ hitsig)
{
    constexpr int BM = AM * 32;
    constexpr int AISS = BM / 32;              // A gload issues per wave
    __shared__ short As[2][BM * 64];
    __shared__ short Bs[2][64 * 64];
    const int tid = threadIdx.x, wave = tid >> 6, lane = tid & 63;
    const int lrow = lane & 15, lq = lane >> 4;
    int bid = blockIdx.x;
    int tiles_m = M / BM;
    int mpx = tiles_m >> 3;
    int xcd = bid & 7, idx = bid >> 3;
    int mt = xcd * mpx + (idx % mpx);
    int nt = idx / mpx;
    const int m0 = mt * BM, n0 = nt * 64;
    const int wm = (wave >> 1) * (AM * 16), wn = (wave & 1) * 32;
    const int K2 = K - Ks;

    // staging lane geometry (R14-verified): row sub-index l8 (row&7==l8),
    // physical slot lane&7; source col slot pre-XORed -> swz64 reads.
    const int l8 = lane >> 3;
    const int cs = ((lane & 7) ^ l8) << 3;

    auto stageA = [&](int k0, int bu) {
#pragma unroll
        for (int u = 0; u < AISS; u++) {
            int r = wave * (AISS * 8) + u * 8 + l8;
            int ka = k0 + cs;
            const short* gp = (ka < Ks)
                ? A1 + (size_t)(m0 + r) * Ks + ka
                : A2 + (size_t)(m0 + r) * K2 + (ka - Ks);
            short* lp = &As[bu][wave * (AISS * 512) + u * 512];
            __builtin_amdgcn_global_load_lds((guint*)gp, (suint*)lp, 16, 0, 0);
        }
    };
    auto stageB = [&](int k0, int bu) {
#pragma unroll
        for (int u = 0; u < 2; u++) {
            int r = wave * 16 + u * 8 + l8;
            const short* gp = BT + (size_t)(n0 + r) * K + k0 + cs;
            short* lp = &Bs[bu][wave * 1024 + u * 512];
            __builtin_amdgcn_global_load_lds((guint*)gp, (suint*)lp, 16, 0, 0);
        }
    };

    stageA(0, 0); stageB(0, 0);
    __syncthreads();                     // buf0 resident
    f4 acc[AM][2] = {};
    const int nsteps = K >> 6;
    int cur = 0;

    for (int t = 0; t < nsteps; t++) {
        if (t + 1 < nsteps) {            // issue next tile; flies over MFMAs
            stageA((t + 1) << 6, cur ^ 1);
            stageB((t + 1) << 6, cur ^ 1);
        }
        __builtin_amdgcn_sched_barrier(0);  // keep issue order structural
#pragma unroll
        for (int kh = 0; kh < 2; kh++) {
            short8 af[AM], bfv[2];
#pragma unroll
            for (int i = 0; i < AM; i++)
                af[i] = *(short8*)&As[cur][swz64(wm + i * 16 + lrow, kh * 4 + lq)];
#pragma unroll
            for (int j = 0; j < 2; j++)
                bfv[j] = *(short8*)&Bs[cur][swz64(wn + j * 16 + lrow, kh * 4 + lq)];
#pragma unroll
            for (int i = 0; i < AM; i++)
#pragma unroll
                for (int j = 0; j < 2; j++)
                    acc[i][j] = __builtin_amdgcn_mfma_f32_16x16x32_bf16(
                        af[i], bfv[j], acc[i][j], 0, 0, 0);
        }
        __syncthreads();                 // drain loads (t+1 resident); readers done
        cur ^= 1;
    }

    if (epi == 3) {
#pragma unroll
        for (int i = 0; i < AM; i++) {
#pragma unroll
            for (int r = 0; r < 4; r++) {
                int row = m0 + wm + i * 16 + lq * 4 + r;
                float gp = 0.f;
#pragma unroll
                for (int j = 0; j < 2; j++) {
                    int col = n0 + wn + j * 16 + lrow;
                    float v = acc[i][j][r] + ent[row] * w1e[col] + bias[col];
                    float sv = v * __builtin_amdgcn_rcpf(1.f + __expf(-v));  // silu
                    gp += sv * altw[col];                                    // altw = Wg2
                }
                gp += __shfl_xor(gp, 1);
                gp += __shfl_xor(gp, 2);
                gp += __shfl_xor(gp, 4);
                gp += __shfl_xor(gp, 8);
                if (lrow == 0) atomicAdd(&C[row], gp);
            }
        }
        return;
    }

#pragma unroll
    for (int i = 0; i < AM; i++) {
#pragma unroll
        for (int r = 0; r < 4; r++) {
            int row = m0 + wm + i * 16 + lq * 4 + r;
            float w0 = 0.f, w1 = 0.f, hs = 0.f;
            if (epi == 5) { w0 = altw[row * 2]; w1 = altw[row * 2 + 1]; hs = hitsig[row]; }
#pragma unroll
            for (int j = 0; j < 2; j++) {
                int col = n0 + wn + j * 16 + lrow;
                float v = acc[i][j][r];
                if (epi == 0) {
                    C[(size_t)row * N + col] = v;
                } else if (epi == 1) {
                    v += resid[(size_t)row * N + col];
                    C[(size_t)row * N + col] = v;
                    Cb1[(size_t)row * N + col] = f2bf(v);
                } else if (epi == 2) {
                    if (col < 1024) Cb1[(size_t)row * 1024 + col] = f2bf(v);
                    else            Cb2[(size_t)row * 1024 + col - 1024] = f2bf(v);
                } else {   // 5: interleaved combine (alt pair in adjacent lanes)
                    float other = __shfl_xor(v, 1);
                    if ((lane & 1) == 0) {
                        float cv = (w0 * v + w1 * other) * hs;
                        Cb1[(size_t)row * 1024 + (col >> 1)] = f2bf(cv);
                    }
                }
            }
        }
    }
}

// ---------------------------------------------------------------------------
// Fused vtrans (blocks 0..1023) + ax (1024..1279).
// ---------------------------------------------------------------------------
__global__ __launch_bounds__(256) void vx_k(
    const short* __restrict__ vb, short* __restrict__ vtg,
    const short* __restrict__ nodes_bf, const float* __restrict__ arity_w,
    float* __restrict__ ax)
{
    const int bid = blockIdx.x;
    const int tid = threadIdx.x;
    __shared__ short tile[64 * 72];

    if (bid < 1024) {
        const int b = bid >> 8, h = (bid >> 4) & 15, t0 = (bid & 15) * 64;
        const int row = tid >> 2, c = (tid & 3) * 16;
        const short* p = vb + (size_t)(b * T_ + t0 + row) * D_ + h * 64 + c;
        *(short8*)&tile[row * 72 + c + 0] = *(const short8*)(p + 0);
        *(short8*)&tile[row * 72 + c + 8] = *(const short8*)(p + 8);
        __syncthreads();
        short8 o0, o1;
#pragma unroll
        for (int i = 0; i < 8; i++) o0[i] = tile[(c + i) * 72 + row];
#pragma unroll
        for (int i = 0; i < 8; i++) o1[i] = tile[(c + 8 + i) * 72 + row];
        short* q = vtg + (size_t)((b * H_ + h) * 64 + row) * T_ + t0 + c;
        *(short8*)(q + 0) = o0;
        *(short8*)(q + 8) = o1;
        return;
    }
    {
        int idx = (bid - 1024) * 256 + tid;
        int t = idx & (T_ - 1);
        int h = (idx >> 10) & (H_ - 1);
        int b = idx >> 14;
        const short* np_ = nodes_bf + (((size_t)b * T_ + t) * H_ + h) * HD_;
        float s = 0.f;
#pragma unroll
        for (int d = 0; d < HD_; d += 8) {
            short8 n8 = *(const short8*)&np_[d];
#pragma unroll
            for (int q = 0; q < 8; q++) s += bf2f(n8[q]) * arity_w[h * HD_ + d + q];
        }
        ax[idx] = s;
    }
}

// ---------------------------------------------------------------------------
// MFMA flash attention v9 (R9-proven, byte-for-byte).
// ---------------------------------------------------------------------------
__global__ __launch_bounds__(256) void attn9_k(
    const short* __restrict__ nodes_bf, const short* __restrict__ vtg,
    const float* __restrict__ ax, short* __restrict__ attnp)
{
    const int b = blockIdx.z, h = blockIdx.y, t0 = blockIdx.x * 64;
    const int tid = threadIdx.x;
    const int wave = tid >> 6, lane = tid & 63;
    const int lrow = lane & 15, lq = lane >> 4;
    const int wm = wave * 16;
    const int row = tid >> 2, c4 = tid & 3;

    __shared__ short Ns[2][64 * 64];
    __shared__ short Vt[2][64 * 64];
    __shared__ short Pm[64 * 64];

    // Q fragment: one strided global load, no LDS round-trip
    const short* qp = nodes_bf + (size_t)(b * T_ + t0 + wm + lrow) * D_ + h * 64;
    const short8 bt0 = *(const short8*)(qp + lq * 8);
    const short8 bt1 = *(const short8*)(qp + 32 + lq * 8);
    const float at8 = ax[(size_t)(b * H_ + h) * T_ + t0 + wm + lrow] * 0.125f;

    const short* np0 = nodes_bf + (size_t)(b * T_ + row) * D_ + h * 64 + c4 * 16;
    const short* vp0 = vtg + (size_t)((b * H_ + h) * 64 + row) * T_ + c4 * 16;
    const float* axp_ = ax + (size_t)(b * H_ + h) * T_;

    short8 vn0, vn1, vv0, vv1;
    f4 axv[4];
    auto preload = [&](int s0) {
        const short* np = np0 + (size_t)s0 * D_;
        const short* vp = vp0 + s0;
        vn0 = *(const short8*)(np + 0);
        vn1 = *(const short8*)(np + 8);
        vv0 = *(const short8*)(vp + 0);
        vv1 = *(const short8*)(vp + 8);
#pragma unroll
        for (int j = 0; j < 4; j++)
            axv[j] = *(const f4*)&axp_[s0 + j * 16 + lq * 4];
    };

    preload(0);

    float l_reg = 0.f;
    f4 O[4] = {};
    f4 axc[4];

    for (int t = 0; t < T_ / 64; t++) {
        const int cur = t & 1;
        // stage regs (loaded last iter) into buf[cur]; prev readers of this
        // buffer finished before barrier(t-1).
        *(short8*)&Ns[cur][swz64(row, 2 * c4 + 0)] = vn0;
        *(short8*)&Ns[cur][swz64(row, 2 * c4 + 1)] = vn1;
        *(short8*)&Vt[cur][swz64(row, 2 * c4 + 0)] = vv0;
        *(short8*)&Vt[cur][swz64(row, 2 * c4 + 1)] = vv1;
#pragma unroll
        for (int j = 0; j < 4; j++) axc[j] = axv[j];    // current tile's ax
        __syncthreads();                       // stage visible; ONE barrier/tile
        if (t + 1 < T_ / 64) preload((t + 1) * 64);  // in flight over compute
        __builtin_amdgcn_sched_barrier(0);     // pin loads before compute

        float psum = 0.f;
#pragma unroll
        for (int j = 0; j < 4; j++) {
            short8 a0 = *(short8*)&Ns[cur][swz64(j * 16 + lrow, lq)];
            short8 a1 = *(short8*)&Ns[cur][swz64(j * 16 + lrow, 4 + lq)];
            f4 s = {0.f, 0.f, 0.f, 0.f};
            __builtin_amdgcn_s_setprio(1);
            s = __builtin_amdgcn_mfma_f32_16x16x32_bf16(a0, bt0, s, 0, 0, 0);
            s = __builtin_amdgcn_mfma_f32_16x16x32_bf16(a1, bt1, s, 0, 0, 0);
            __builtin_amdgcn_s_setprio(0);
            // mK = K*sigmoid_poly(z), K = 0.125*log2(e); p = exp2(score * mK)
            float p0, p1, p2, p3;
            {
                float z, zz, t1, mK;
                z = fmaf(axc[j][0], 0.125f, at8); zz = z * z;
                t1 = fmaf(zz, -0.0037570183f, 0.04508422f);
                mK = fmaf(z, t1, 0.09016844f);
                p0 = __builtin_amdgcn_exp2f(s[0] * mK);
                z = fmaf(axc[j][1], 0.125f, at8); zz = z * z;
                t1 = fmaf(zz, -0.0037570183f, 0.04508422f);
                mK = fmaf(z, t1, 0.09016844f);
                p1 = __builtin_amdgcn_exp2f(s[1] * mK);
                z = fmaf(axc[j][2], 0.125f, at8); zz = z * z;
                t1 = fmaf(zz, -0.0037570183f, 0.04508422f);
                mK = fmaf(z, t1, 0.09016844f);
                p2 = __builtin_amdgcn_exp2f(s[2] * mK);
                z = fmaf(axc[j][3], 0.125f, at8); zz = z * z;
                t1 = fmaf(zz, -0.0037570183f, 0.04508422f);
                mK = fmaf(z, t1, 0.09016844f);
                p3 = __builtin_amdgcn_exp2f(s[3] * mK);
            }
            psum += (p0 + p1) + (p2 + p3);
            unsigned u0, u1;
            asm("v_cvt_pk_bf16_f32 %0, %1, %2" : "=v"(u0) : "v"(p0), "v"(p1));
            asm("v_cvt_pk_bf16_f32 %0, %1, %2" : "=v"(u1) : "v"(p2), "v"(p3));
            uint2v uu; uu[0] = u0; uu[1] = u1;
            *(uint2v*)&Pm[swz64(wm + lrow, 2 * j + (lq >> 1)) + (lq & 1) * 4] = uu;
        }
        l_reg += psum;
        // Pm rows are wave-private: no block barrier needed before PV.

        short8 pa0 = *(short8*)&Pm[swz64(wm + lrow, lq)];
        short8 pa1 = *(short8*)&Pm[swz64(wm + lrow, 4 + lq)];
        __builtin_amdgcn_s_setprio(1);
#pragma unroll
        for (int dj = 0; dj < 4; dj++) {
            short8 v0 = *(short8*)&Vt[cur][swz64(dj * 16 + lrow, lq)];
            short8 v1 = *(short8*)&Vt[cur][swz64(dj * 16 + lrow, 4 + lq)];
            O[dj] = __builtin_amdgcn_mfma_f32_16x16x32_bf16(pa0, v0, O[dj], 0, 0, 0);
            O[dj] = __builtin_amdgcn_mfma_f32_16x16x32_bf16(pa1, v1, O[dj], 0, 0, 0);
        }
        __builtin_amdgcn_s_setprio(0);
    }

    // deferred cross-lane row-sum (lanes with equal lrow hold the same t-row)
    l_reg += __shfl_xor(l_reg, 16);
    l_reg += __shfl_xor(l_reg, 32);

    float linv[4];
#pragma unroll
    for (int r = 0; r < 4; r++)
        linv[r] = __builtin_amdgcn_rcpf(__shfl(l_reg, lq * 4 + r));
#pragma unroll
    for (int dj = 0; dj < 4; dj++)
#pragma unroll
        for (int r = 0; r < 4; r++)
            attnp[(size_t)(b * T_ + t0 + wm + lq * 4 + r) * D_ + h * 64 + dj * 16 + lrow] =
                f2bf(O[dj][r] * linv[r]);
}

// ---------------------------------------------------------------------------
// Per-token tail: entropy, event norm, sim (LDS), butterfly top-4, softmaxes.
// Also zeroes gsum[m] ahead of the Wg1 gemm's fused-gate atomics.
// ---------------------------------------------------------------------------
__global__ __launch_bounds__(256) void token2_k(
    const float* __restrict__ evlg, const float* __restrict__ pn,
    const float* __restrict__ patterns, const float* __restrict__ W_alt,
    const float* __restrict__ log_temp,
    float* __restrict__ entn, float* __restrict__ altw, float* __restrict__ hitsig,
    float* __restrict__ gsum)
{
    const int tid = threadIdx.x, wave = tid >> 6, lane = tid & 63;
    __shared__ float pn_sh[64 * 68];
    __shared__ float pat_sh[64 * 68];
    __shared__ float en_sh[4][68];
    {
        int row = tid >> 2, c = (tid & 3) * 16;
#pragma unroll
        for (int u = 0; u < 4; u++) {
            *(float4*)&pn_sh[row * 68 + c + u * 4]  = *(const float4*)&pn[row * 64 + c + u * 4];
            *(float4*)&pat_sh[row * 68 + c + u * 4] = *(const float4*)&patterns[row * 64 + c + u * 4];
        }
    }
    float temp = expf(log_temp[0]);
    temp = fminf(fmaxf(temp, 0.01f), 10.f);
    const float tinv = 1.f / temp;
    __syncthreads();

#pragma unroll
    for (int rep = 0; rep < 2; rep++) {
        const int m = blockIdx.x * 8 + wave * 2 + rep;
        float ev = evlg[(size_t)m * 128 + lane];
        float ss = ev * ev;
        for (int off = 1; off < 64; off <<= 1) ss += __shfl_xor(ss, off);
        float en = ev * __builtin_amdgcn_rcpf(fmaxf(sqrtf(ss), 1e-12f));
        en_sh[wave][lane] = en;
        float entv;
        {
            float lgt = evlg[(size_t)m * 128 + 64 + (lane & 7)];
            float mx = lgt;
            for (int off = 1; off < 8; off <<= 1) mx = fmaxf(mx, __shfl_xor(mx, off));
            float p = __expf(lgt - mx);
            float sum = p;
            for (int off = 1; off < 8; off <<= 1) sum += __shfl_xor(sum, off);
            float pi = p / sum;
            float term = -pi * __logf(pi + 1e-10f);
            float e = term;
            for (int off = 1; off < 8; off <<= 1) e += __shfl_xor(e, off);
            entv = e * 0.4808983f;   // 1/ln(8)
        }
        float sim = 0.f;
#pragma unroll
        for (int u = 0; u < 16; u++) {
            float4 e4 = *(float4*)&en_sh[wave][u * 4];
            float4 p4 = *(float4*)&pn_sh[lane * 68 + u * 4];
            sim += e4.x * p4.x + e4.y * p4.y + e4.z * p4.z + e4.w * p4.w;
        }
        float v = sim;
        float tv[NH_]; int tix[NH_];
#pragma unroll
        for (int kk = 0; kk < NH_; kk++) {
            float mv = v; int mi = lane;
            if (v == -1e30f) mi = 127;
            for (int off = 1; off < 64; off <<= 1) {
                float ov = __shfl_xor(mv, off);
                int   oi = __shfl_xor(mi, off);
                if (ov > mv || (ov == mv && oi < mi)) { mv = ov; mi = oi; }
            }
            tv[kk] = mv; tix[kk] = mi;
            if (lane == mi) v = -1e30f;
        }
        float hmx = tv[0];
        float hw[NH_], hsum = 0.f;
#pragma unroll
        for (int kk = 0; kk < NH_; kk++) { hw[kk] = __expf((tv[kk] - hmx) * tinv); hsum += hw[kk]; }
        float hsr = __builtin_amdgcn_rcpf(hsum);
        float wp = 0.f;
#pragma unroll
        for (int kk = 0; kk < NH_; kk++) wp += hw[kk] * hsr * pat_sh[tix[kk] * 68 + lane];
        float a0 = wp * W_alt[lane * 2 + 0];
        float a1 = wp * W_alt[lane * 2 + 1];
        for (int off = 1; off < 64; off <<= 1) {
            a0 += __shfl_xor(a0, off);
            a1 += __shfl_xor(a1, off);
        }
        a0 *= tinv; a1 *= tinv;
        float amx = fmaxf(a0, a1);
        float e0 = __expf(a0 - amx), e1 = __expf(a1 - amx);
        if (lane == 0) {
            float zr = __builtin_amdgcn_rcpf(e0 + e1);
            altw[m * 2 + 0] = e0 * zr;
            altw[m * 2 + 1] = e1 * zr;
            hitsig[m] = __builtin_amdgcn_rcpf(1.f + __expf(-tv[0]));
            entn[m] = entv;
            gsum[m] = 0.f;
        }
    }
}

// ---------------------------------------------------------------------------
// gate final: g = sigmoid(gsum[m] + bg2); out = x1 + g * actions.
// ---------------------------------------------------------------------------
__global__ __launch_bounds__(256) void gate2_k(
    const float* __restrict__ gsum, const float* __restrict__ bg2,
    const float* __restrict__ x1, const short* __restrict__ actions_bf,
    float* __restrict__ out)
{
    const int m = blockIdx.x, tid = threadIdx.x;
    float g = 1.f / (1.f + __expf(-(gsum[m] + bg2[0])));
    size_t i = (size_t)m * D_ + tid * 4;
    float4 xv = *(const float4*)&x1[i];
    short4v av = *(const short4v*)&actions_bf[i];
    float4 o;
    o.x = xv.x + g * bf2f(av[0]);
    o.y = xv.y + g * bf2f(av[1]);
    o.z = xv.z + g * bf2f(av[2]);
    o.w = xv.w + g * bf2f(av[3]);
    *(float4*)&out[i] = o;
}

// ---------------------------------------------------------------------------
extern "C" void kernel_launch(void* const* d_in, const int* in_sizes, int n_in,
                              void* d_out, int out_size, void* d_ws, size_t ws_size,
                              hipStream_t stream)
{
    const float* x        = (const float*)d_in[0];
    const float* W_node   = (const float*)d_in[1];
    const float* W_value  = (const float*)d_in[2];
    const float* W_out    = (const float*)d_in[3];
    const float* arity_w  = (const float*)d_in[4];
    const float* W_event  = (const float*)d_in[5];
    const float* W_type   = (const float*)d_in[6];
    const float* patterns = (const float*)d_in[7];
    const float* W_act    = (const float*)d_in[8];
    const float* W_alt    = (const float*)d_in[9];
    const float* log_temp = (const float*)d_in[10];
    const float* Wg1      = (const float*)d_in[11];
    const float* bg1      = (const float*)d_in[12];
    const float* Wg2      = (const float*)d_in[13];
    const float* bg2      = (const float*)d_in[14];
    float* out = (float*)d_out;

    const int M = B_ * T_;                          // 4096
    // --- fp32 ---
    float* x1     = (float*)d_ws;                   // 4M floats
    float* evlg   = x1 + 4194304;                   // 512K  [M][128]
    float* axp    = evlg + 524288;                  // 64K
    float* pn     = axp + 65536;
    float* entn   = pn + 4096;
    float* altw   = entn + 4096;
    float* hitsig = altw + 8192;
    float* gsum   = axp;                            // aliases axp (dead post-attn)
    // --- bf16 ---
    short* big       = (short*)(hitsig + 4096);
    short* xbf       = big;                         // 4M (x cast; attn out)
    short* nodes_bf  = big + 1 * 4194304;
    short* values_bf = big + 2 * 4194304;
    short* vtg       = big + 3 * 4194304;           // later actions_bf
    short* x1_bf     = big + 4 * 4194304;
    short* wts       = big + 5 * 4194304;
    short* WnvT  = wts;                             // 2M  ([2048][1024])
    short* WoT   = wts + 2 * 1048576;               // 1M
    short* WaT   = wts + 3 * 1048576;               // 2M  interleaved [2048][1024]
    short* Wg1T  = wts + 5 * 1048576;               // 2M  ([1024][2048])
    short* BTe   = wts + 7 * 1048576;               // 128K shorts ([128][1024])
    short* actions_bf = vtg;

    dim3 blk(256);
    dim3 g_bh(T_ / 64, H_, B_);

    TJobs jb;   // bases offset +2048 (castx occupies blocks 0..2047)
    jb.j[0] = {W_node,            WnvT,           1024, 1024, 1, 0, 2048};
    jb.j[1] = {W_value,           WnvT + 1048576, 1024, 1024, 1, 0, 2304};
    jb.j[2] = {W_out,             WoT,            1024, 1024, 1, 0, 2560};
    jb.j[3] = {W_act,             WaT,            1024, 1024, 2, 0, 2816};
    jb.j[4] = {W_act + 1048576,   WaT,            1024, 1024, 2, 1, 3072};
    jb.j[5] = {Wg1,               Wg1T,           2048, 1024, 1, 0, 3328};
    jb.j[6] = {W_event,           BTe,            1024,   64, 1, 0, 3840};
    prep_k<<<3904, blk, 0, stream>>>(x, xbf, jb, W_type, BTe, patterns, pn);

    // QKV fused: N=2048, 64x64 tiles -> 2048 blocks (R16-proven)
    gemm11<2><<<2048, blk, 0, stream>>>(xbf, xbf, D_, WnvT,
        nullptr, nodes_bf, values_bf, M, 2048, D_, 2,
        nullptr, nullptr, nullptr, nullptr, nullptr, nullptr);
    vx_k<<<1280, blk, 0, stream>>>(values_bf, vtg, nodes_bf, arity_w, axp);
    attn9_k<<<g_bh, blk, 0, stream>>>(nodes_bf, vtg, axp, xbf);   // xbf = attn out
    // x1 = attn@W_out + x: 64x64 tiles -> 1024 blocks
    gemm11<2><<<1024, blk, 0, stream>>>(xbf, xbf, D_, WoT,
        x1, x1_bf, nullptr, M, D_, D_, 1,
        x, nullptr, nullptr, nullptr, nullptr, nullptr);
    // events + type logits: N=128, 64x64 tiles -> 128 blocks
    gemm11<2><<<128, blk, 0, stream>>>(x1_bf, x1_bf, D_, BTe,
        evlg, nullptr, nullptr, M, 128, D_, 0,
        nullptr, nullptr, nullptr, nullptr, nullptr, nullptr);
    token2_k<<<M / 8, blk, 0, stream>>>(evlg, pn, patterns, W_alt, log_temp,
                                        entn, altw, hitsig, gsum);
    // actions: N=2048 interleaved, 64x64 tiles -> 2048 blocks (epi 5)
    gemm11<2><<<2048, blk, 0, stream>>>(x1_bf, x1_bf, D_, WaT,
        nullptr, actions_bf, nullptr, M, 2048, D_, 5,
        nullptr, nullptr, nullptr, nullptr, altw, hitsig);
    // Wg1 gemm with FUSED gate dot: gsum[row] += silu(...)*Wg2[col]
    gemm11<2><<<1024, blk, 0, stream>>>(x1_bf, actions_bf, D_, Wg1T,
        gsum, nullptr, nullptr, M, D_, 2048, 3,
        nullptr, entn, Wg1 + (size_t)2048 * D_, bg1, Wg2, nullptr);
    gate2_k<<<M, blk, 0, stream>>>(gsum, bg2, x1, actions_bf, out);
}